// Round 3
// baseline (17064.117 us; speedup 1.0000x reference)
//
#include <hip/hip_runtime.h>

typedef unsigned short u16;
typedef __attribute__((ext_vector_type(8))) short bf8;     // 8 x bf16 (4 VGPRs)
typedef __attribute__((ext_vector_type(4))) float f4;      // MFMA C/D frag
typedef __attribute__((ext_vector_type(4))) unsigned int u32x4;

struct Params {
  const int* inputs; const int* targets;
  const void *enc_emb, *enc_Wih, *enc_Whh, *enc_bias, *enc_ln_g, *enc_ln_b;
  const void *dec_emb, *att_W, *att_b, *att_v;
  const void *dec_Wih0, *dec_Wih1, *dec_Whh, *dec_bias, *dec_ln_g, *dec_ln_b;
  const void *fc_W, *fc_b;
  void* out;
};

// -------- canonical weight/vector buffers (filled by k_conv each launch) -----
__device__ __align__(16) u16 gb_enc_emb[3072000];
__device__ __align__(16) u16 gb_dec_emb[3072000];
__device__ __align__(16) u16 gb_enc_Wih[2097152];
__device__ __align__(16) u16 gb_enc_Whh[2097152];
__device__ __align__(16) u16 gb_dec_Wih0[2097152];
__device__ __align__(16) u16 gb_dec_Wih1[1048576];
__device__ __align__(16) u16 gb_dec_Whh[2097152];
__device__ __align__(16) u16 gb_att_W[524288];
__device__ __align__(16) u16 gb_fc_W[3072000];
__device__ float gc_enc_bias[4096], gc_dec_bias[4096];
__device__ float gc_enc_ln_g[512], gc_enc_ln_b[512], gc_dec_ln_g[512], gc_dec_ln_b[512];
__device__ float gc_att_b[512], gc_att_v[512], gc_fc_b[6000];

// ---------------- state scratch in device globals ----------------------------
__device__ __align__(16) u16 g_Hdec[4 * 32 * 512];       // [slot][layer][b][h]
__device__ __align__(16) u16 g_Henc[4 * 32 * 512];
__device__ __align__(16) u16 g_ctx[32 * 512];
__device__ __align__(16) u16 g_outsb5[5 * 1024 * 512];   // [s-1][t*32+b][h]
__device__ __align__(16) u16 g_lnouts5[5 * 1024 * 512];
__device__ __align__(16) u16 g_encraw[1024 * 512];       // [b*32+t][h]
__device__ __align__(16) u16 g_encouts[2][1024 * 512];
__device__ __align__(16) u16 g_encpart[2][1024 * 512];
__device__ __align__(16) float g_Cdec[2 * 32 * 512];
__device__ __align__(16) float g_Cenc[2 * 32 * 512];
__device__ __align__(16) float g_pqp[32 * 32 * 512];     // [u][b][h]
__device__ int g_masks[6 * 32 * 32];
__device__ int g_dtoks[6 * 32 * 32];                     // [s][t][b]
__device__ int g_etoks[5 * 32 * 32];

// precomputed emb-input gate partials (bias folded in), layout [gstep][c 2048][b 32] f32
__device__ __align__(16) float g_dpre[192 * 2048 * 32];
__device__ __align__(16) float g_epre[160 * 2048 * 32];

// ---------------- grid barrier state (zero-init at module load) --------------
__device__ unsigned g_flags[128 * 16];                   // one flag per block, 64B stride
__device__ unsigned g_gen;

// LDS layout for k_persist (dynamic shared)
#define GL_OFF   0          // gate exchange: 4*32*17*4 = 8704 B (also att scratch)
#define HL_OFF   8704       // h slice f32: 32*16*4 = 2048 B
#define SEG1_OFF 10752      // weight seg 1: 4 waves * 16 rows * 512 u16 = 65536 B
#define SEG2_OFF 76288      // weight seg 2: 65536 B
#define LDS_TOTAL 141824

__device__ __forceinline__ float b2f(u16 u) { union { unsigned i; float f; } v; v.i = ((unsigned)u) << 16; return v.f; }
__device__ __forceinline__ u16 f2b(float f) {
  union { float f; unsigned i; } v; v.f = f;
  unsigned x = v.i;
  return (u16)((x + 0x7fffu + ((x >> 16) & 1u)) >> 16);    // RNE
}
__device__ __forceinline__ float sigf(float x) { return 1.f / (1.f + __expf(-x)); }
__device__ __forceinline__ float tanhf_(float x) { float e = __expf(2.f * x); return 1.f - 2.f / (e + 1.f); }

// dtype probe: enc_ln_g == ones. f32 -> first dword 0x3F800000; bf16 pair -> 0x3F803F80
__device__ __forceinline__ bool is_f32(const Params& P) {
  return *(const unsigned*)P.enc_ln_g == 0x3F800000u;
}

// ---------------- device-scope grid barrier (128 blocks) ----------------------
__device__ __forceinline__ void gridbar(int blk, int tid, unsigned& g) {
  g += 1;
  __syncthreads();
  if (blk == 0) {
    if (tid >= 1 && tid < 128) {
      while (__hip_atomic_load(&g_flags[tid * 16], __ATOMIC_RELAXED, __HIP_MEMORY_SCOPE_AGENT) != g)
        __builtin_amdgcn_s_sleep(1);
    }
    __syncthreads();
    __builtin_amdgcn_fence(__ATOMIC_ACQUIRE, "agent");
    if (tid == 0)
      __hip_atomic_store(&g_gen, g, __ATOMIC_RELEASE, __HIP_MEMORY_SCOPE_AGENT);
  } else {
    if (tid == 0) {
      __hip_atomic_store(&g_flags[blk * 16], g, __ATOMIC_RELEASE, __HIP_MEMORY_SCOPE_AGENT);
      while (__hip_atomic_load(&g_gen, __ATOMIC_RELAXED, __HIP_MEMORY_SCOPE_AGENT) != g)
        __builtin_amdgcn_s_sleep(1);
    }
    __syncthreads();
    __builtin_amdgcn_fence(__ATOMIC_ACQUIRE, "agent");
  }
}

struct Acc2 { f4 lo, hi; };

// C[0:32,0:16] += A[0:32,0:K] * Wp[0:16,0:K]^T   (A rows contiguous, ld=512; W global)
__device__ __forceinline__ void mm_seg(Acc2& a, const u16* A, const u16* Wp, int ldW, int K, int lane) {
  const int n = lane & 15, q = lane >> 4;
  const u16* a0 = A + n * 512 + q * 8;
  const u16* a1 = a0 + 16 * 512;
  const u16* bp = Wp + n * ldW + q * 8;
  for (int k = 0; k < K; k += 32) {
    bf8 va0 = *(const bf8*)(a0 + k);
    bf8 va1 = *(const bf8*)(a1 + k);
    bf8 vb  = *(const bf8*)(bp + k);
    a.lo = __builtin_amdgcn_mfma_f32_16x16x32_bf16(va0, vb, a.lo, 0, 0, 0);
    a.hi = __builtin_amdgcn_mfma_f32_16x16x32_bf16(va1, vb, a.hi, 0, 0, 0);
  }
}

// A rows gathered from an embedding table by token id (K = 512 fixed, W global)
__device__ __forceinline__ void mm_tok(Acc2& a, const u16* emb, const int* toks,
                                       const u16* Wp, int ldW, int lane) {
  const int n = lane & 15, q = lane >> 4;
  const u16* a0 = emb + (size_t)toks[n] * 512 + q * 8;
  const u16* a1 = emb + (size_t)toks[n + 16] * 512 + q * 8;
  const u16* bp = Wp + n * ldW + q * 8;
  for (int k = 0; k < 512; k += 32) {
    bf8 va0 = *(const bf8*)(a0 + k);
    bf8 va1 = *(const bf8*)(a1 + k);
    bf8 vb  = *(const bf8*)(bp + k);
    a.lo = __builtin_amdgcn_mfma_f32_16x16x32_bf16(va0, vb, a.lo, 0, 0, 0);
    a.hi = __builtin_amdgcn_mfma_f32_16x16x32_bf16(va1, vb, a.hi, 0, 0, 0);
  }
}

// A[32][512] from global, W slice from LDS (XOR-swizzled 16B chunks), K=512
__device__ __forceinline__ void mm_seg_lds(Acc2& a, const u16* A, const u16* Wl, int lane) {
  const int n = lane & 15, q = lane >> 4, x = n & 7;
  const u16* a0 = A + n * 512 + q * 8;
  const u16* a1 = a0 + 8192;
  const u16* wr = Wl + n * 512;
  for (int ki = 0; ki < 16; ki++) {
    bf8 va0 = *(const bf8*)(a0 + ki * 32);
    bf8 va1 = *(const bf8*)(a1 + ki * 32);
    bf8 vb  = *(const bf8*)(wr + (((q + 4 * ki) ^ x) << 3));
    a.lo = __builtin_amdgcn_mfma_f32_16x16x32_bf16(va0, vb, a.lo, 0, 0, 0);
    a.hi = __builtin_amdgcn_mfma_f32_16x16x32_bf16(va1, vb, a.hi, 0, 0, 0);
  }
}

// stage a 64KB weight slice (4 waves x 16 rows x 512 cols) into LDS, swizzled
__device__ __forceinline__ void stage_seg(u16* lds_seg, const u16* W, int ldW, int c0, int u, int tid) {
  for (int idx = tid; idx < 4096; idx += 256) {
    int w = idx >> 10, n = (idx >> 6) & 15, ch = idx & 63;
    const u16* src = W + (size_t)(w * 512 + u * 16 + n) * ldW + c0 + ch * 8;
    u16* dst = lds_seg + ((w * 16 + n) * 64 + (ch ^ (n & 7))) * 8;
    *(u32x4*)dst = *(const u32x4*)src;
  }
}

// One LSTM layer step, weights in LDS. wave g computes gate g (i,f,g,o).
__device__ __forceinline__ void lstm_lds(char* smem, int u, int lane, int wave, int tid,
    const float* pre,            // [2048 c][32 b] f32 gate partials (or null)
    const float* bias,           // used when pre==null
    const u16* A1,               // global [32][512] paired with SEG1 (or null)
    const u16* A2,               // global [32][512] paired with SEG2 (or null)
    float* Cst, u16* Hout,
    u16* Xtra, int xmode, int t,
    bool do_pqp, float* pqp)
{
  float* gl = (float*)(smem + GL_OFF);             // [4][32][17]
  float* hl = (float*)(smem + HL_OFF);             // [32][16]
  const u16* seg1 = (const u16*)(smem + SEG1_OFF) + wave * 8192;
  const u16* seg2 = (const u16*)(smem + SEG2_OFF) + wave * 8192;
  const int n = lane & 15, q = lane >> 4;
  const int colbase = wave * 512 + u * 16;
  Acc2 acc;
  if (pre) {
    const float* pb = pre + (size_t)(colbase + n) * 32;
    acc.lo = *(const f4*)(pb + q * 4);
    acc.hi = *(const f4*)(pb + q * 4 + 16);
  } else {
    float bv = bias[colbase + n];
    f4 bi = { bv, bv, bv, bv };
    acc.lo = bi; acc.hi = bi;
  }
  if (A1) mm_seg_lds(acc, A1, seg1, lane);
  if (A2) mm_seg_lds(acc, A2, seg2, lane);
#pragma unroll
  for (int r = 0; r < 4; r++) {
    gl[(wave * 32 + q * 4 + r) * 17 + n]      = acc.lo[r];
    gl[(wave * 32 + 16 + q * 4 + r) * 17 + n] = acc.hi[r];
  }
  __syncthreads();
  for (int p = tid; p < 512; p += 256) {
    int b = p >> 4, nn = p & 15, hc = u * 16 + nn;
    float iv = gl[(0 * 32 + b) * 17 + nn];
    float fv = gl[(1 * 32 + b) * 17 + nn];
    float gv = gl[(2 * 32 + b) * 17 + nn];
    float ov = gl[(3 * 32 + b) * 17 + nn];
    float c2 = sigf(fv) * Cst[b * 512 + hc] + sigf(iv) * tanhf_(gv);
    float h2 = sigf(ov) * tanhf_(c2);
    Cst[b * 512 + hc] = c2;
    u16 hb = f2b(h2);
    Hout[b * 512 + hc] = hb;
    if (xmode == 1)      Xtra[(t * 32 + b) * 512 + hc] = hb;   // dec outs [t][b][h]
    else if (xmode == 2) Xtra[(b * 32 + t) * 512 + hc] = hb;   // enc raw  [b][t][h]
    if (do_pqp) hl[b * 16 + nn] = h2;
  }
  if (do_pqp) {
    __syncthreads();
    // pqp[u][b][h] = sum_{k in slice u} h1[b,k] * attW[h,k]  (attW streamed, 16KB)
    for (int h = tid; h < 512; h += 256) {
      float wl[16];
#pragma unroll
      for (int j = 0; j < 16; j++) wl[j] = b2f(gb_att_W[h * 1024 + u * 16 + j]);
      for (int b = 0; b < 32; b++) {
        float s = 0.f;
#pragma unroll
        for (int j = 0; j < 16; j++) s += hl[b * 16 + j] * wl[j];
        pqp[(u * 32 + b) * 512 + h] = s;
      }
    }
  }
}

// attention for batch row b (one block), result -> g_ctx[b][:]
__device__ __forceinline__ void att_dev(char* smem, int b, int s, int lane, int wave, int tid)
{
  float* qp = (float*)(smem + GL_OFF); float* sc = qp + 512; float* av = sc + 32;
  const int sprev = (s & 1) ^ 1;
  const u16* ep_prev = g_encpart[sprev];
  const u16* eo_prev = g_encouts[sprev];

  for (int h = tid; h < 512; h += 256) {
    float ssum = 0.f;
#pragma unroll 4
    for (int u = 0; u < 32; u++) ssum += g_pqp[(u * 32 + b) * 512 + h];
    qp[h] = ssum;
  }
  __syncthreads();
  for (int tt = wave; tt < 32; tt += 4) {
    float part = 0.f;
    for (int h = lane; h < 512; h += 64)
      part += tanhf_(qp[h] + b2f(ep_prev[(b * 32 + tt) * 512 + h])) * gc_att_v[h];
#pragma unroll
    for (int off = 32; off; off >>= 1) part += __shfl_xor(part, off, 64);
    if (lane == 0) sc[tt] = g_masks[(s * 32 + b) * 32 + tt] ? -1e9f : fminf(fmaxf(part, -1e30f), 1e30f);
  }
  __syncthreads();
  if (wave == 0) {
    float v = (lane < 32) ? sc[lane] : -3e38f;
    float m = v;
#pragma unroll
    for (int off = 32; off; off >>= 1) m = fmaxf(m, __shfl_xor(m, off, 64));
    float e = (lane < 32) ? __expf(v - m) : 0.f;
    float ssum = e;
#pragma unroll
    for (int off = 32; off; off >>= 1) ssum += __shfl_xor(ssum, off, 64);
    if (lane < 32) av[lane] = e / ssum;
  }
  __syncthreads();
  for (int h = tid; h < 512; h += 256) {
    float ssum = 0.f;
#pragma unroll 4
    for (int tt = 0; tt < 32; tt++) ssum += av[tt] * b2f(eo_prev[(b * 32 + tt) * 512 + h]);
    g_ctx[b * 512 + h] = f2b(ssum);
  }
}

// ---------------------------- kernels ----------------------------------------

// big-tensor dtype normalization: f32->bf16 convert or bf16 passthrough copy
__global__ void __launch_bounds__(256) k_conv(Params P)
{
  const bool f32 = is_f32(P);
  int c = blockIdx.x * 256 + threadIdx.x;    // chunk of 8 elements
  const void* src; u16* dst;
  if (c < 384000)                 { src = P.enc_emb;  dst = gb_enc_emb;  }
  else if ((c -= 384000) < 384000){ src = P.dec_emb;  dst = gb_dec_emb;  }
  else if ((c -= 384000) < 262144){ src = P.enc_Wih;  dst = gb_enc_Wih;  }
  else if ((c -= 262144) < 262144){ src = P.enc_Whh;  dst = gb_enc_Whh;  }
  else if ((c -= 262144) < 262144){ src = P.dec_Wih0; dst = gb_dec_Wih0; }
  else if ((c -= 262144) < 131072){ src = P.dec_Wih1; dst = gb_dec_Wih1; }
  else if ((c -= 131072) < 262144){ src = P.dec_Whh;  dst = gb_dec_Whh;  }
  else if ((c -= 262144) < 65536) { src = P.att_W;    dst = gb_att_W;    }
  else                            { c -= 65536; src = P.fc_W; dst = gb_fc_W; }
  if (f32) {
    const float* s = (const float*)src + (size_t)c * 8;
    union { u32x4 v; u16 o[8]; } u;
#pragma unroll
    for (int j = 0; j < 8; j++) u.o[j] = f2b(s[j]);
    *(u32x4*)(dst + (size_t)c * 8) = u.v;
  } else {
    ((u32x4*)dst)[c] = ((const u32x4*)src)[c];
  }
}

// small vectors -> canonical f32
__global__ void __launch_bounds__(256) k_conv_small(Params P)
{
  const bool f32 = is_f32(P);
  int i = blockIdx.x * 256 + threadIdx.x;
  const void* src; float* dst;
  if (i < 4096)                 { src = P.enc_bias; dst = gc_enc_bias; }
  else if ((i -= 4096) < 4096)  { src = P.dec_bias; dst = gc_dec_bias; }
  else if ((i -= 4096) < 512)   { src = P.enc_ln_g; dst = gc_enc_ln_g; }
  else if ((i -= 512) < 512)    { src = P.enc_ln_b; dst = gc_enc_ln_b; }
  else if ((i -= 512) < 512)    { src = P.dec_ln_g; dst = gc_dec_ln_g; }
  else if ((i -= 512) < 512)    { src = P.dec_ln_b; dst = gc_dec_ln_b; }
  else if ((i -= 512) < 512)    { src = P.att_b;    dst = gc_att_b;    }
  else if ((i -= 512) < 512)    { src = P.att_v;    dst = gc_att_v;    }
  else if ((i -= 512) < 6000)   { src = P.fc_b;     dst = gc_fc_b;     }
  else return;
  dst[i] = f32 ? ((const float*)src)[i] : b2f(((const u16*)src)[i]);
}

__global__ void __launch_bounds__(256) k_setup(Params P)
{
  const int gtid = blockIdx.x * 256 + threadIdx.x;
  if (gtid < 6144) {                      // dtoks[s][t][b]
    int s = gtid >> 10, rem = gtid & 1023, t = rem >> 5, b = rem & 31;
    int tok = (t == 0) ? 1
            : ((s == 0) ? P.inputs[b * 192 + (t - 1)] : P.targets[b * 160 + (s - 1) * 32 + (t - 1)]);
    g_dtoks[gtid] = tok;
  } else if (gtid < 6144 + 5120) {        // etoks[s][t][b]
    int gi = gtid - 6144;
    int s = gi >> 10, rem = gi & 1023, t = rem >> 5, b = rem & 31;
    g_etoks[gi] = (s == 0) ? P.inputs[b * 192 + t] : P.targets[b * 160 + (s - 1) * 32 + t];
  }
  if (blockIdx.x >= 64 && blockIdx.x < 224 && threadIdx.x == 0) {  // masks[s][b][t]
    int w = blockIdx.x - 64;
    int s = 1 + (w >> 5), b = w & 31;
    int seen = 0;
    g_masks[(s * 32 + b) * 32 + 0] = 0;
    for (int t2 = 1; t2 < 32; t2++) {
      int tk = (s == 1) ? P.inputs[b * 192 + (t2 - 1)] : P.targets[b * 160 + (s - 2) * 32 + (t2 - 1)];
      seen |= (tk == 2 || tk == 3) ? 1 : 0;
      g_masks[(s * 32 + b) * 32 + t2] = seen;
    }
  }
  u32x4 z = { 0u, 0u, 0u, 0u };
  if (gtid < 8192)  ((u32x4*)g_Hdec)[gtid] = z;
  if (gtid >= 8192 && gtid < 16384) ((u32x4*)g_Henc)[gtid - 8192] = z;
  if (gtid >= 16384 && gtid < 18432) ((u32x4*)g_ctx)[gtid - 16384] = z;
  if (gtid >= 18432 && gtid < 26624) ((u32x4*)g_Cdec)[gtid - 18432] = z;
  if (gtid >= 26624 && gtid < 34816) ((u32x4*)g_Cenc)[gtid - 26624] = z;
}

// precompute emb-input gate partials for all timesteps:
//   g_dpre[gstep][c][b] = dec_bias_L0[c] + emb_dec[dtok] . Wih0[c, 0:512]
//   g_epre[gstep][c][b] = enc_bias_L0[c] + emb_enc[etok] . WihE0[c, 0:512]
__global__ void __launch_bounds__(256) k_pre()
{
  const int blk = blockIdx.x, tid = threadIdx.x;
  const int lane = tid & 63, wave = tid >> 6;
  const int n = lane & 15, q = lane >> 4;
  const bool dec = blk < 1536;
  const int idx = dec ? blk : blk - 1536;
  const int u = idx & 31, gq = idx >> 5;
  const u16* emb = dec ? gb_dec_emb : gb_enc_emb;
  const u16* W   = dec ? gb_dec_Wih0 : gb_enc_Wih;
  const int ldW  = dec ? 1024 : 512;
  const float* bias = dec ? gc_dec_bias : gc_enc_bias;
  float* pre = dec ? g_dpre : g_epre;
  const int* toks = dec ? g_dtoks : g_etoks;
  const int colbase = wave * 512 + u * 16;
  for (int gi = 0; gi < 4; gi++) {
    int gstep = gq * 4 + gi;
    float bv = bias[colbase + n];
    f4 bi = { bv, bv, bv, bv };
    Acc2 acc; acc.lo = bi; acc.hi = bi;
    mm_tok(acc, emb, toks + gstep * 32, W + (size_t)colbase * ldW, ldW, lane);
    float* dst = pre + ((size_t)gstep * 2048 + colbase + n) * 32;
    *(f4*)(dst + q * 4) = acc.lo;
    *(f4*)(dst + q * 4 + 16) = acc.hi;
  }
}

// ---------------- the persistent recurrence kernel ---------------------------
// 128 blocks x 256 threads, 1/CU (LDS 138.5KB). Roles by blk>>5:
//   0: ENC0 (u=blk&31)    LDS SEG1 = enc_Whh L0 slice
//   1: ENC1               LDS SEG1 = enc_Wih L1, SEG2 = enc_Whh L1
//   2: DEC0 (+att in P1)  LDS SEG1 = dec_Wih0 ctx half, SEG2 = dec_Whh L0
//   3: DEC1 (+pqp)        LDS SEG1 = dec_Wih1, SEG2 = dec_Whh L1
// Per timestep: P1 {encL0 | att} ; P2 {encL1 | decL0} ; P3 {decL1+pqp | encLN@t31}
// Sentence boundary adds one encpart phase. Weights never leave LDS -> the
// per-barrier L2 invalidation only costs small state re-reads.
__global__ void __launch_bounds__(256) k_persist()
{
  extern __shared__ char smem[];
  const int blk = blockIdx.x, tid = threadIdx.x;
  const int lane = tid & 63, wave = tid >> 6;
  const int role = blk >> 5, u = blk & 31;
  unsigned g = __hip_atomic_load(&g_gen, __ATOMIC_RELAXED, __HIP_MEMORY_SCOPE_AGENT);

  // ---- stage persistent weight slices into LDS (once) ----
  u16* s1 = (u16*)(smem + SEG1_OFF);
  u16* s2 = (u16*)(smem + SEG2_OFF);
  if (role == 0) {
    stage_seg(s1, gb_enc_Whh, 512, 0, u, tid);
  } else if (role == 1) {
    stage_seg(s1, gb_enc_Wih + 1048576, 512, 0, u, tid);
    stage_seg(s2, gb_enc_Whh + 1048576, 512, 0, u, tid);
  } else if (role == 2) {
    stage_seg(s1, gb_dec_Wih0, 1024, 512, u, tid);
    stage_seg(s2, gb_dec_Whh, 512, 0, u, tid);
  } else {
    stage_seg(s1, gb_dec_Wih1, 512, 0, u, tid);
    stage_seg(s2, gb_dec_Whh + 1048576, 512, 0, u, tid);
  }
  __syncthreads();

  for (int s = 0; s < 6; s++) {
    for (int t = 0; t < 32; t++) {
      const int gstep = s * 32 + t, si = gstep & 1, so = si ^ 1;
      // ---------------- P1: encL0 | att ----------------
      if (role == 0) {
        if (s < 5)
          lstm_lds(smem, u, lane, wave, tid,
            g_epre + (size_t)gstep * 65536, nullptr,
            g_Henc + (si * 2 + 0) * 16384, nullptr,
            g_Cenc, g_Henc + (so * 2 + 0) * 16384,
            nullptr, 0, t, false, nullptr);
      } else if (role == 2 && s > 0) {
        att_dev(smem, u, s, lane, wave, tid);
      }
      gridbar(blk, tid, g);
      // ---------------- P2: encL1 | decL0 ----------------
      if (role == 1) {
        if (s < 5)
          lstm_lds(smem, u, lane, wave, tid,
            nullptr, gc_enc_bias + 2048,
            g_Henc + (so * 2 + 0) * 16384, g_Henc + (si * 2 + 1) * 16384,
            g_Cenc + 16384, g_Henc + (so * 2 + 1) * 16384,
            g_encraw, 2, t, false, nullptr);
      } else if (role == 2) {
        lstm_lds(smem, u, lane, wave, tid,
          g_dpre + (size_t)gstep * 65536, nullptr,
          (s > 0) ? g_ctx : nullptr, g_Hdec + (si * 2 + 0) * 16384,
          g_Cdec, g_Hdec + (so * 2 + 0) * 16384,
          nullptr, 0, t, false, nullptr);
      }
      gridbar(blk, tid, g);
      // ---------------- P3: decL1 (+pqp) | encLN at t==31 ----------------
      if (role == 3) {
        int dp = ((s > 0 && t < 31) || (t == 31 && s < 5)) ? 1 : 0;
        u16* outp = (s >= 1) ? (g_outsb5 + (size_t)(s - 1) * 524288) : nullptr;
        lstm_lds(smem, u, lane, wave, tid,
          nullptr, gc_dec_bias + 2048,
          g_Hdec + (so * 2 + 0) * 16384, g_Hdec + (si * 2 + 1) * 16384,
          g_Cdec + 16384, g_Hdec + (so * 2 + 1) * 16384,
          outp, outp ? 1 : 0, t, dp != 0, g_pqp);
      } else if (role < 2 && t == 31 && s < 5) {
        // enc LayerNorm: 1024 rows over blocks 0..63 (16 rows each)
        u16* out = g_encouts[s & 1];
#pragma unroll
        for (int rr = 0; rr < 4; rr++) {
          int row = blk * 16 + wave * 4 + rr;
          const u16* x = g_encraw + row * 512 + lane * 8;
          float xs[8]; float sm = 0.f, sq = 0.f;
#pragma unroll
          for (int j = 0; j < 8; j++) { xs[j] = b2f(x[j]); sm += xs[j]; sq += xs[j] * xs[j]; }
#pragma unroll
          for (int off = 32; off; off >>= 1) { sm += __shfl_xor(sm, off, 64); sq += __shfl_xor(sq, off, 64); }
          float mean = sm * (1.f / 512.f);
          float var = fmaxf(sq * (1.f / 512.f) - mean * mean, 0.f);
          float rstd = rsqrtf(var + 1e-5f);
          u16* o = out + row * 512 + lane * 8;
#pragma unroll
          for (int j = 0; j < 8; j++) {
            int k = lane * 8 + j;
            o[j] = f2b((xs[j] - mean) * rstd * gc_enc_ln_g[k] + gc_enc_ln_b[k]);
          }
        }
      }
      gridbar(blk, tid, g);
      // ---------------- sentence boundary: encpart ----------------
      if (t == 31 && s < 5) {
        if (role < 2) {
          // encpart[b][t][h] = enc_outs . att_W[:,512:] + att_b  (blocks 0..63)
          const u16* eo_cur = g_encouts[s & 1];
          u16* ep_cur = g_encpart[s & 1];
          const int n = lane & 15, q = lane >> 4;
          int rc = blk >> 3, cc = blk & 7;
          int nbase = cc * 64 + wave * 16;
          float bv = gc_att_b[nbase + n];
#pragma unroll
          for (int mt = 0; mt < 4; mt++) {
            int rowbase = rc * 128 + mt * 32;
            f4 bi = { bv, bv, bv, bv };
            Acc2 acc; acc.lo = bi; acc.hi = bi;
            mm_seg(acc, eo_cur + rowbase * 512, gb_att_W + nbase * 1024 + 512, 1024, 512, lane);
#pragma unroll
            for (int r = 0; r < 4; r++) {
              int row = rowbase + q * 4 + r;
              ep_cur[row * 512 + nbase + n]        = f2b(acc.lo[r]);
              ep_cur[(row + 16) * 512 + nbase + n] = f2b(acc.hi[r]);
            }
          }
        }
        gridbar(blk, tid, g);
      }
    }
  }
}

// ---- deferred decoder LayerNorm over all 5 sentences (5120 rows) ------------
__global__ void __launch_bounds__(256) k_ln_post(Params P)
{
  const int blk = blockIdx.x, tid = threadIdx.x;
  const int lane = tid & 63, wave = tid >> 6;
#pragma unroll
  for (int rr = 0; rr < 2; rr++) {
    int row = blk * 8 + wave * 2 + rr;                    // 0..5119
    const u16* x = g_outsb5 + (size_t)row * 512 + lane * 8;
    float xs[8]; float sm = 0.f, sq = 0.f;
#pragma unroll
    for (int j = 0; j < 8; j++) { xs[j] = b2f(x[j]); sm += xs[j]; sq += xs[j] * xs[j]; }
#pragma unroll
    for (int off = 32; off; off >>= 1) { sm += __shfl_xor(sm, off, 64); sq += __shfl_xor(sq, off, 64); }
    float mean = sm * (1.f / 512.f);
    float var = fmaxf(sq * (1.f / 512.f) - mean * mean, 0.f);
    float rstd = rsqrtf(var + 1e-5f);
    u16* o = g_lnouts5 + (size_t)row * 512 + lane * 8;
#pragma unroll
    for (int j = 0; j < 8; j++) {
      int k = lane * 8 + j;
      o[j] = f2b((xs[j] - mean) * rstd * gc_dec_ln_g[k] + gc_dec_ln_b[k]);
    }
  }
}

// ---- deferred FC over all 5 sentences: logits -> out[b][s-1][t][v] ----------
__global__ void __launch_bounds__(256) k_fc_post(Params P)
{
  __shared__ char sbuf[65536];
  const int blk0 = blockIdx.x, tid = threadIdx.x;
  const int sidx = blk0 / 192, blk = blk0 % 192;
  const int lane = tid & 63, wave = tid >> 6;
  const int n = lane & 15, q = lane >> 4;
  const bool f32o = is_f32(P);
  const u16* lnin = g_lnouts5 + (size_t)sidx * 524288;
  u16* As = (u16*)sbuf;                  // [64 rows][512], XOR-swizzled 16B chunks
  int mc = blk / 12, ncc = blk % 12;
  int mrow0 = mc * 64;
  for (int idx = tid; idx < 64 * 64; idx += 256) {
    int row = idx >> 6, ch = idx & 63;
    int phys = ch ^ (row & 7);
    *(u32x4*)(As + (row * 64 + phys) * 8) = *(const u32x4*)(lnin + (size_t)(mrow0 + row) * 512 + ch * 8);
  }
  __syncthreads();
  f4 acc[4][8];
#pragma unroll
  for (int j = 0; j < 8; j++) {
    int c = ncc * 512 + wave * 128 + j * 16 + n;
    float bv = (c < 6000) ? gc_fc_b[c] : 0.f;
    f4 bi = { bv, bv, bv, bv };
#pragma unroll
    for (int mt = 0; mt < 4; mt++) acc[mt][j] = bi;
  }
  for (int kt = 0; kt < 16; kt++) {
    bf8 a[4];
#pragma unroll
    for (int mt = 0; mt < 4; mt++) {
      int row = mt * 16 + n;
      int ch = kt * 4 + q;
      int phys = ch ^ (row & 7);
      a[mt] = *(const bf8*)(As + (row * 64 + phys) * 8);
    }
#pragma unroll
    for (int j = 0; j < 8; j++) {
      int c = ncc * 512 + wave * 128 + j * 16 + n;
      int brow = (c < 6000) ? c : 5999;
      bf8 vb = *(const bf8*)(gb_fc_W + brow * 512 + kt * 32 + q * 8);
#pragma unroll
      for (int mt = 0; mt < 4; mt++)
        acc[mt][j] = __builtin_amdgcn_mfma_f32_16x16x32_bf16(a[mt], vb, acc[mt][j], 0, 0, 0);
    }
  }
#pragma unroll
  for (int j = 0; j < 8; j++) {
    int c = ncc * 512 + wave * 128 + j * 16 + n;
    if (c < 6000) {
#pragma unroll
      for (int mt = 0; mt < 4; mt++) {
#pragma unroll
        for (int r = 0; r < 4; r++) {
          int rix = mrow0 + mt * 16 + q * 4 + r;   // row = t*32 + b
          int tt = rix >> 5, b = rix & 31;
          size_t oidx = (size_t)((b * 5 + sidx) * 32 + tt) * 6000 + c;
          float v = acc[mt][j][r];
          if (f32o) ((float*)P.out)[oidx] = v;
          else      ((u16*)P.out)[oidx] = f2b(v);
        }
      }
    }
  }
}

extern "C" void kernel_launch(void* const* d_in, const int* in_sizes, int n_in,
                              void* d_out, int out_size, void* d_ws, size_t ws_size,
                              hipStream_t stream) {
  Params P;
  P.inputs   = (const int*)d_in[0];
  P.targets  = (const int*)d_in[1];
  P.enc_emb  = d_in[2];
  P.enc_Wih  = d_in[3];
  P.enc_Whh  = d_in[4];
  P.enc_bias = d_in[5];
  P.enc_ln_g = d_in[6];
  P.enc_ln_b = d_in[7];
  P.dec_emb  = d_in[8];
  P.att_W    = d_in[9];
  P.att_b    = d_in[10];
  P.att_v    = d_in[11];
  P.dec_Wih0 = d_in[12];
  P.dec_Wih1 = d_in[13];
  P.dec_Whh  = d_in[14];
  P.dec_bias = d_in[15];
  P.dec_ln_g = d_in[16];
  P.dec_ln_b = d_in[17];
  P.fc_W     = d_in[18];
  P.fc_b     = d_in[19];
  P.out = d_out;

  static bool attr_done = false;
  if (!attr_done) {
    hipFuncSetAttribute((const void*)k_persist,
                        hipFuncAttributeMaxDynamicSharedMemorySize, LDS_TOTAL);
    attr_done = true;
  }

  hipLaunchKernelGGL(k_conv, dim3(9364), dim3(256), 0, stream, P);
  hipLaunchKernelGGL(k_conv_small, dim3(68), dim3(256), 0, stream, P);
  hipLaunchKernelGGL(k_setup, dim3(256), dim3(256), 0, stream, P);
  hipLaunchKernelGGL(k_pre, dim3(2816), dim3(256), 0, stream);
  hipLaunchKernelGGL(k_persist, dim3(128), dim3(256), LDS_TOTAL, stream);
  hipLaunchKernelGGL(k_ln_post, dim3(640), dim3(256), 0, stream, P);
  hipLaunchKernelGGL(k_fc_post, dim3(960), dim3(256), 0, stream, P);
}

// Round 6
// 12557.803 us; speedup vs baseline: 1.3588x; 1.3588x over previous
//
#include <hip/hip_runtime.h>

typedef unsigned short u16;
typedef __attribute__((ext_vector_type(8))) short bf8;     // 8 x bf16 (4 VGPRs)
typedef __attribute__((ext_vector_type(4))) float f4;      // MFMA C/D frag
typedef __attribute__((ext_vector_type(4))) unsigned int u32x4;

struct Params {
  const int* inputs; const int* targets;
  const void *enc_emb, *enc_Wih, *enc_Whh, *enc_bias, *enc_ln_g, *enc_ln_b;
  const void *dec_emb, *att_W, *att_b, *att_v;
  const void *dec_Wih0, *dec_Wih1, *dec_Whh, *dec_bias, *dec_ln_g, *dec_ln_b;
  const void *fc_W, *fc_b;
  void* out;
};

// -------- canonical weight/vector buffers (filled by k_conv each launch) -----
__device__ __align__(16) u16 gb_enc_emb[3072000];
__device__ __align__(16) u16 gb_dec_emb[3072000];
__device__ __align__(16) u16 gb_enc_Wih[2097152];
__device__ __align__(16) u16 gb_enc_Whh[2097152];
__device__ __align__(16) u16 gb_dec_Wih0[2097152];
__device__ __align__(16) u16 gb_dec_Wih1[1048576];
__device__ __align__(16) u16 gb_dec_Whh[2097152];
__device__ __align__(16) u16 gb_att_W[524288];
__device__ __align__(16) u16 gb_fc_W[3072000];
__device__ float gc_enc_bias[4096], gc_dec_bias[4096];
__device__ float gc_enc_ln_g[512], gc_enc_ln_b[512], gc_dec_ln_g[512], gc_dec_ln_b[512];
__device__ float gc_att_b[512], gc_att_v[512], gc_fc_b[6000];

// ---------------- state scratch in device globals ----------------------------
__device__ __align__(16) u16 g_Hdec[4 * 32 * 512];       // [slot][layer][b][h]
__device__ __align__(16) u16 g_Henc[4 * 32 * 512];
__device__ __align__(16) u16 g_ctx[32 * 512];
__device__ __align__(16) u16 g_outsb5[5 * 1024 * 512];   // [s-1][t*32+b][h]
__device__ __align__(16) u16 g_lnouts5[5 * 1024 * 512];
__device__ __align__(16) u16 g_encraw5[5 * 1024 * 512];  // [s][b*32+t][h]
__device__ __align__(16) u16 g_encouts5[5 * 1024 * 512]; // [s][b*32+t][h]
__device__ __align__(16) u16 g_encpart5[5 * 1024 * 512];
__device__ __align__(16) float g_pqp[32 * 512 * 32];     // [b][h][u]  f32
__device__ int g_masks[6 * 32 * 32];
__device__ int g_dtoks[6 * 32 * 32];                     // [s][t][b]
__device__ int g_etoks[5 * 32 * 32];

// precomputed emb-input gate partials (bias folded in), layout [gstep][c 2048][b 32] f32
__device__ __align__(16) float g_dpre[192 * 2048 * 32];
__device__ __align__(16) float g_epre[160 * 2048 * 32];

// ---------------- barrier state (zero-init; monotonic across launches) -------
__device__ unsigned g_flags_enc[64 * 32], g_acks_enc[64 * 32];
__device__ unsigned g_flags_dec[64 * 32], g_acks_dec[64 * 32];
__device__ unsigned g_gen0_enc, g_gen0_dec, g_encdone, g_epoch;

// LDS layout for k_persist (dynamic shared)
#define GL_OFF   0          // gate exchange: 4*32*17*4 = 8704 B (also att scratch)
#define HL_OFF   8704       // h slice f32: 32*16*4 = 2048 B
#define CL_OFF   10752      // C state f32: 32*16*4 = 2048 B (block-private)
#define SEG1_OFF 12800      // weight seg 1: 4 waves * 16 rows * 512 u16 = 65536 B
#define SEG2_OFF 78336      // weight seg 2: 65536 B
#define LDS_TOTAL 143872

#define SPIN_CAP (1 << 27)   // deadlock -> wrong-answer safety valve (~seconds)

__device__ __forceinline__ float b2f(u16 u) { union { unsigned i; float f; } v; v.i = ((unsigned)u) << 16; return v.f; }
__device__ __forceinline__ u16 f2b(float f) {
  union { float f; unsigned i; } v; v.f = f;
  unsigned x = v.i;
  return (u16)((x + 0x7fffu + ((x >> 16) & 1u)) >> 16);    // RNE
}
__device__ __forceinline__ float sigf(float x) { return 1.f / (1.f + __expf(-x)); }
__device__ __forceinline__ float tanhf_(float x) { float e = __expf(2.f * x); return 1.f - 2.f / (e + 1.f); }

__device__ __forceinline__ bool is_f32(const Params& P) {
  return *(const unsigned*)P.enc_ln_g == 0x3F800000u;
}

// ---------------- LLC-coherent (sc0 sc1) access helpers ----------------------
#define VWAIT(N) do { asm volatile("s_waitcnt vmcnt(" #N ")" ::: "memory"); \
                      __builtin_amdgcn_sched_barrier(0); } while (0)

__device__ __forceinline__ void sc_ld(bf8& d, const u16* p) {
  asm volatile("global_load_dwordx4 %0, %1, off sc0 sc1" : "=v"(d) : "v"(p));
}
__device__ __forceinline__ void sc_ld_f4(f4& d, const float* p) {
  asm volatile("global_load_dwordx4 %0, %1, off sc0 sc1" : "=v"(d) : "v"(p));
}
__device__ __forceinline__ void sc_st16(u16* p, u32x4 v) {
  asm volatile("global_store_dwordx4 %0, %1, off sc0 sc1" :: "v"(p), "v"(v) : "memory");
}
__device__ __forceinline__ void sc_st_u16(u16* p, u16 v) {
  unsigned vv = v;
  asm volatile("global_store_short %0, %1, off sc0 sc1" :: "v"(p), "v"(vv) : "memory");
}
__device__ __forceinline__ void sc_st_f32(float* p, float v) {
  asm volatile("global_store_dword %0, %1, off sc0 sc1" :: "v"(p), "v"(v) : "memory");
}
__device__ __forceinline__ unsigned sc_ld_u32(const unsigned* p) {
  unsigned r;
  asm volatile("global_load_dword %0, %1, off sc0 sc1\n\ts_waitcnt vmcnt(0)"
               : "=v"(r) : "v"(p) : "memory");
  return r;
}
__device__ __forceinline__ void sc_st_u32(unsigned* p, unsigned v) {
  asm volatile("global_store_dword %0, %1, off sc0 sc1\n\ts_waitcnt vmcnt(0)"
               :: "v"(p), "v"(v) : "memory");
}

// ---------------- fence-free domain barrier (64 blocks) -----------------------
// Every wave drains its own VMEM (vmcnt(0)) before s_barrier; arrival flag is an
// sc store; leader lanes each poll ONE follower flag then ack on the follower's
// private line. No cache invalidation anywhere. Spins are capped so a protocol
// bug shows as wrong-answer (with counters), not an opaque hang.
__device__ __forceinline__ void bar_dom(unsigned* flags, unsigned* acks, int lb, int tid, unsigned& g) {
  g += 1;
  asm volatile("s_waitcnt vmcnt(0)" ::: "memory");
  __syncthreads();
  if (lb == 0) {
    if (tid >= 1 && tid < 64) {
      int it = 0;
      while (sc_ld_u32(flags + tid * 32) != g && ++it < SPIN_CAP) __builtin_amdgcn_s_sleep(2);
      sc_st_u32(acks + tid * 32, g);
    }
    __syncthreads();
  } else {
    if (tid == 0) {
      sc_st_u32(flags + lb * 32, g);
      int it = 0;
      while (sc_ld_u32(acks + lb * 32) != g && ++it < SPIN_CAP) __builtin_amdgcn_s_sleep(2);
    }
    __syncthreads();
  }
}

struct Acc2 { f4 lo, hi; };

// C[0:32,0:16] += A[0:32,0:K] * Wp[0:16,0:K]^T (normal cached loads; immutable A/W)
__device__ __forceinline__ void mm_seg(Acc2& a, const u16* A, const u16* Wp, int ldW, int K, int lane) {
  const int n = lane & 15, q = lane >> 4;
  const u16* a0 = A + n * 512 + q * 8;
  const u16* a1 = a0 + 16 * 512;
  const u16* bp = Wp + n * ldW + q * 8;
  for (int k = 0; k < K; k += 32) {
    bf8 va0 = *(const bf8*)(a0 + k);
    bf8 va1 = *(const bf8*)(a1 + k);
    bf8 vb  = *(const bf8*)(bp + k);
    a.lo = __builtin_amdgcn_mfma_f32_16x16x32_bf16(va0, vb, a.lo, 0, 0, 0);
    a.hi = __builtin_amdgcn_mfma_f32_16x16x32_bf16(va1, vb, a.hi, 0, 0, 0);
  }
}

// A rows gathered from an embedding table by token id (K = 512, normal loads)
__device__ __forceinline__ void mm_tok(Acc2& a, const u16* emb, const int* toks,
                                       const u16* Wp, int ldW, int lane) {
  const int n = lane & 15, q = lane >> 4;
  const u16* a0 = emb + (size_t)toks[n] * 512 + q * 8;
  const u16* a1 = emb + (size_t)toks[n + 16] * 512 + q * 8;
  const u16* bp = Wp + n * ldW + q * 8;
  for (int k = 0; k < 512; k += 32) {
    bf8 va0 = *(const bf8*)(a0 + k);
    bf8 va1 = *(const bf8*)(a1 + k);
    bf8 vb  = *(const bf8*)(bp + k);
    a.lo = __builtin_amdgcn_mfma_f32_16x16x32_bf16(va0, vb, a.lo, 0, 0, 0);
    a.hi = __builtin_amdgcn_mfma_f32_16x16x32_bf16(va1, vb, a.hi, 0, 0, 0);
  }
}

// A[32][512] via coherent sc loads (2-deep pipelined, counted vmcnt), W from LDS
__device__ __forceinline__ void mm_seg_llc(Acc2& a, const u16* A, const u16* Wl, int lane) {
  const int n = lane & 15, q = lane >> 4, x = n & 7;
  const u16* a0 = A + n * 512 + q * 8;
  const u16* a1 = a0 + 8192;                 // row n+16
  const u16* wr = Wl + n * 512;
  bf8 r0[2][4], r1[2][4];
#pragma unroll
  for (int j = 0; j < 4; j++) { sc_ld(r0[0][j], a0 + j * 32); sc_ld(r1[0][j], a1 + j * 32); }
#pragma unroll
  for (int c = 0; c < 4; c++) {
    const int pb = c & 1, nb = pb ^ 1;
    if (c < 3) {
#pragma unroll
      for (int j = 0; j < 4; j++) {
        sc_ld(r0[nb][j], a0 + (c + 1) * 128 + j * 32);
        sc_ld(r1[nb][j], a1 + (c + 1) * 128 + j * 32);
      }
      VWAIT(8);
    } else {
      VWAIT(0);
    }
#pragma unroll
    for (int j = 0; j < 4; j++) {
      int ki = c * 4 + j;
      bf8 vb = *(const bf8*)(wr + (((q + 4 * ki) ^ x) << 3));
      a.lo = __builtin_amdgcn_mfma_f32_16x16x32_bf16(r0[pb][j], vb, a.lo, 0, 0, 0);
      a.hi = __builtin_amdgcn_mfma_f32_16x16x32_bf16(r1[pb][j], vb, a.hi, 0, 0, 0);
    }
  }
}

// stage a 64KB weight slice (4 waves x 16 rows x 512 cols) into LDS, swizzled
__device__ __forceinline__ void stage_seg(u16* lds_seg, const u16* W, int ldW, int c0, int u, int tid) {
  for (int idx = tid; idx < 4096; idx += 256) {
    int w = idx >> 10, n = (idx >> 6) & 15, ch = idx & 63;
    const u16* src = W + (size_t)(w * 512 + u * 16 + n) * ldW + c0 + ch * 8;
    u16* dst = lds_seg + ((w * 16 + n) * 64 + (ch ^ (n & 7))) * 8;
    *(u32x4*)dst = *(const u32x4*)src;
  }
}

// One LSTM layer step: weights in LDS, A via sc loads, C in LDS, H out via sc.
__device__ __forceinline__ void lstm_llc(char* smem, int u, int lane, int wave, int tid,
    const float* pre, const float* bias,
    const u16* A1, const u16* A2,
    u16* Hout, u16* Xtra, int xmode, int t, bool do_pqp)
{
  float* gl = (float*)(smem + GL_OFF);             // [4][32][17]
  float* hl = (float*)(smem + HL_OFF);             // [32][16]
  float* Cl = (float*)(smem + CL_OFF);             // [32][16]
  const u16* seg1 = (const u16*)(smem + SEG1_OFF) + wave * 8192;
  const u16* seg2 = (const u16*)(smem + SEG2_OFF) + wave * 8192;
  const int n = lane & 15, q = lane >> 4;
  const int colbase = wave * 512 + u * 16;
  Acc2 acc;
  if (pre) {
    const float* pb = pre + (size_t)(colbase + n) * 32;
    acc.lo = *(const f4*)(pb + q * 4);
    acc.hi = *(const f4*)(pb + q * 4 + 16);
  } else {
    float bv = bias[colbase + n];
    f4 bi = { bv, bv, bv, bv };
    acc.lo = bi; acc.hi = bi;
  }
  if (A1) mm_seg_llc(acc, A1, seg1, lane);
  if (A2) mm_seg_llc(acc, A2, seg2, lane);
#pragma unroll
  for (int r = 0; r < 4; r++) {
    gl[(wave * 32 + q * 4 + r) * 17 + n]      = acc.lo[r];
    gl[(wave * 32 + 16 + q * 4 + r) * 17 + n] = acc.hi[r];
  }
  __syncthreads();
  for (int p = tid; p < 512; p += 256) {
    int b = p >> 4, nn = p & 15, hc = u * 16 + nn;
    float iv = gl[(0 * 32 + b) * 17 + nn];
    float fv = gl[(1 * 32 + b) * 17 + nn];
    float gv = gl[(2 * 32 + b) * 17 + nn];
    float ov = gl[(3 * 32 + b) * 17 + nn];
    float c2 = sigf(fv) * Cl[b * 16 + nn] + sigf(iv) * tanhf_(gv);
    float h2 = sigf(ov) * tanhf_(c2);
    Cl[b * 16 + nn] = c2;
    u16 hb = f2b(h2);
    sc_st_u16(Hout + b * 512 + hc, hb);
    if (xmode == 1)      Xtra[(t * 32 + b) * 512 + hc] = hb;          // outsb5 (normal)
    else if (xmode == 2) sc_st_u16(Xtra + (b * 32 + t) * 512 + hc, hb); // encraw (sc)
    if (do_pqp) hl[b * 16 + nn] = h2;
  }
  if (do_pqp) {
    __syncthreads();
    // pqp[b][h][u] = sum_{k in slice u} h1[b,k] * attW[h,k]
    for (int h = tid; h < 512; h += 256) {
      float wl[16];
#pragma unroll
      for (int j = 0; j < 16; j++) wl[j] = b2f(gb_att_W[h * 1024 + u * 16 + j]);
      for (int b = 0; b < 32; b++) {
        float sacc = 0.f;
#pragma unroll
        for (int j = 0; j < 16; j++) sacc += hl[b * 16 + j] * wl[j];
        sc_st_f32(g_pqp + ((size_t)b * 512 + h) * 32 + u, sacc);
      }
    }
  }
}

// attention for batch row b (one block), result -> g_ctx[b][:] (sc)
__device__ __forceinline__ void att_llc(char* smem, int b, int s, int lane, int wave, int tid)
{
  float* qp = (float*)(smem + GL_OFF); float* sc = qp + 512; float* av = sc + 32;
  const u16* ep_prev = g_encpart5 + (size_t)(s - 1) * 524288;
  const u16* eo_prev = g_encouts5 + (size_t)(s - 1) * 524288;

  for (int h = tid; h < 512; h += 256) {
    const float* pp = g_pqp + ((size_t)b * 512 + h) * 32;
    f4 r[8];
#pragma unroll
    for (int j = 0; j < 8; j++) sc_ld_f4(r[j], pp + j * 4);
    VWAIT(0);
    f4 ss = r[0];
#pragma unroll
    for (int j = 1; j < 8; j++) ss += r[j];
    qp[h] = ss[0] + ss[1] + ss[2] + ss[3];
  }
  __syncthreads();
  for (int tt = wave; tt < 32; tt += 4) {
    float part = 0.f;
    for (int h = lane; h < 512; h += 64)
      part += tanhf_(qp[h] + b2f(ep_prev[(b * 32 + tt) * 512 + h])) * gc_att_v[h];
#pragma unroll
    for (int off = 32; off; off >>= 1) part += __shfl_xor(part, off, 64);
    if (lane == 0) sc[tt] = g_masks[(s * 32 + b) * 32 + tt] ? -1e9f : fminf(fmaxf(part, -1e30f), 1e30f);
  }
  __syncthreads();
  if (wave == 0) {
    float v = (lane < 32) ? sc[lane] : -3e38f;
    float m = v;
#pragma unroll
    for (int off = 32; off; off >>= 1) m = fmaxf(m, __shfl_xor(m, off, 64));
    float e = (lane < 32) ? __expf(v - m) : 0.f;
    float ssum = e;
#pragma unroll
    for (int off = 32; off; off >>= 1) ssum += __shfl_xor(ssum, off, 64);
    if (lane < 32) av[lane] = e / ssum;
  }
  __syncthreads();
  for (int h = tid; h < 512; h += 256) {
    float ssum = 0.f;
#pragma unroll 4
    for (int tt = 0; tt < 32; tt++) ssum += av[tt] * b2f(eo_prev[(b * 32 + tt) * 512 + h]);
    sc_st_u16(g_ctx + b * 512 + h, f2b(ssum));
  }
}

// ---------------------------- kernels ----------------------------------------

__global__ void __launch_bounds__(256) k_conv(Params P)
{
  const bool f32 = is_f32(P);
  int c = blockIdx.x * 256 + threadIdx.x;    // chunk of 8 elements
  const void* src; u16* dst;
  if (c < 384000)                 { src = P.enc_emb;  dst = gb_enc_emb;  }
  else if ((c -= 384000) < 384000){ src = P.dec_emb;  dst = gb_dec_emb;  }
  else if ((c -= 384000) < 262144){ src = P.enc_Wih;  dst = gb_enc_Wih;  }
  else if ((c -= 262144) < 262144){ src = P.enc_Whh;  dst = gb_enc_Whh;  }
  else if ((c -= 262144) < 262144){ src = P.dec_Wih0; dst = gb_dec_Wih0; }
  else if ((c -= 262144) < 131072){ src = P.dec_Wih1; dst = gb_dec_Wih1; }
  else if ((c -= 131072) < 262144){ src = P.dec_Whh;  dst = gb_dec_Whh;  }
  else if ((c -= 262144) < 65536) { src = P.att_W;    dst = gb_att_W;    }
  else                            { c -= 65536; src = P.fc_W; dst = gb_fc_W; }
  if (f32) {
    const float* s = (const float*)src + (size_t)c * 8;
    union { u32x4 v; u16 o[8]; } u;
#pragma unroll
    for (int j = 0; j < 8; j++) u.o[j] = f2b(s[j]);
    *(u32x4*)(dst + (size_t)c * 8) = u.v;
  } else {
    ((u32x4*)dst)[c] = ((const u32x4*)src)[c];
  }
}

__global__ void __launch_bounds__(256) k_conv_small(Params P)
{
  const bool f32 = is_f32(P);
  int i = blockIdx.x * 256 + threadIdx.x;
  const void* src; float* dst;
  if (i < 4096)                 { src = P.enc_bias; dst = gc_enc_bias; }
  else if ((i -= 4096) < 4096)  { src = P.dec_bias; dst = gc_dec_bias; }
  else if ((i -= 4096) < 512)   { src = P.enc_ln_g; dst = gc_enc_ln_g; }
  else if ((i -= 512) < 512)    { src = P.enc_ln_b; dst = gc_enc_ln_b; }
  else if ((i -= 512) < 512)    { src = P.dec_ln_g; dst = gc_dec_ln_g; }
  else if ((i -= 512) < 512)    { src = P.dec_ln_b; dst = gc_dec_ln_b; }
  else if ((i -= 512) < 512)    { src = P.att_b;    dst = gc_att_b;    }
  else if ((i -= 512) < 512)    { src = P.att_v;    dst = gc_att_v;    }
  else if ((i -= 512) < 6000)   { src = P.fc_b;     dst = gc_fc_b;     }
  else return;
  dst[i] = f32 ? ((const float*)src)[i] : b2f(((const u16*)src)[i]);
}

__global__ void __launch_bounds__(256) k_setup(Params P)
{
  const int gtid = blockIdx.x * 256 + threadIdx.x;
  if (gtid == 0) g_epoch = g_epoch + 1;
  if (gtid < 6144) {                      // dtoks[s][t][b]
    int s = gtid >> 10, rem = gtid & 1023, t = rem >> 5, b = rem & 31;
    int tok = (t == 0) ? 1
            : ((s == 0) ? P.inputs[b * 192 + (t - 1)] : P.targets[b * 160 + (s - 1) * 32 + (t - 1)]);
    g_dtoks[gtid] = tok;
  } else if (gtid < 6144 + 5120) {        // etoks[s][t][b]
    int gi = gtid - 6144;
    int s = gi >> 10, rem = gi & 1023, t = rem >> 5, b = rem & 31;
    g_etoks[gi] = (s == 0) ? P.inputs[b * 192 + t] : P.targets[b * 160 + (s - 1) * 32 + t];
  }
  if (blockIdx.x >= 64 && blockIdx.x < 224 && threadIdx.x == 0) {  // masks[s][b][t]
    int w = blockIdx.x - 64;
    int s = 1 + (w >> 5), b = w & 31;
    int seen = 0;
    g_masks[(s * 32 + b) * 32 + 0] = 0;
    for (int t2 = 1; t2 < 32; t2++) {
      int tk = (s == 1) ? P.inputs[b * 192 + (t2 - 1)] : P.targets[b * 160 + (s - 2) * 32 + (t2 - 1)];
      seen |= (tk == 2 || tk == 3) ? 1 : 0;
      g_masks[(s * 32 + b) * 32 + t2] = seen;
    }
  }
  u32x4 z = { 0u, 0u, 0u, 0u };
  if (gtid < 8192)  ((u32x4*)g_Hdec)[gtid] = z;
  if (gtid >= 8192 && gtid < 16384) ((u32x4*)g_Henc)[gtid - 8192] = z;
  if (gtid >= 16384 && gtid < 18432) ((u32x4*)g_ctx)[gtid - 16384] = z;
}

// precompute emb-input gate partials for all timesteps
__global__ void __launch_bounds__(256) k_pre()
{
  const int blk = blockIdx.x, tid = threadIdx.x;
  const int lane = tid & 63, wave = tid >> 6;
  const int n = lane & 15, q = lane >> 4;
  const bool dec = blk < 1536;
  const int idx = dec ? blk : blk - 1536;
  const int u = idx & 31, gq = idx >> 5;
  const u16* emb = dec ? gb_dec_emb : gb_enc_emb;
  const u16* W   = dec ? gb_dec_Wih0 : gb_enc_Wih;
  const int ldW  = dec ? 1024 : 512;
  const float* bias = dec ? gc_dec_bias : gc_enc_bias;
  float* pre = dec ? g_dpre : g_epre;
  const int* toks = dec ? g_dtoks : g_etoks;
  const int colbase = wave * 512 + u * 16;
  for (int gi = 0; gi < 4; gi++) {
    int gstep = gq * 4 + gi;
    float bv = bias[colbase + n];
    f4 bi = { bv, bv, bv, bv };
    Acc2 acc; acc.lo = bi; acc.hi = bi;
    mm_tok(acc, emb, toks + gstep * 32, W + (size_t)colbase * ldW, ldW, lane);
    float* dst = pre + ((size_t)gstep * 2048 + colbase + n) * 32;
    *(f4*)(dst + q * 4) = acc.lo;
    *(f4*)(dst + q * 4 + 16) = acc.hi;
  }
}

// ---------------- the persistent recurrence kernel ---------------------------
// 128 blocks, 1/CU. Two independent barrier domains:
//   enc = blocks 0-63  (role 0: enc L0, role 1: enc L1), 2 phases/step
//   dec = blocks 64-127 (role 0: att+dec L0, role 1: dec L1), 3 phases/step
// enc runs ahead; dec waits on a per-sentence enc_done flag. No cache fences:
// all racy state moves via sc0 sc1 (LLC) accesses; read-only data stays L2-hot.
__global__ void __launch_bounds__(256) k_persist()
{
  extern __shared__ char smem[];
  const int blk = blockIdx.x, tid = threadIdx.x;
  const int lane = tid & 63, wave = tid >> 6;
  const bool encdom = blk < 64;
  const int lb = encdom ? blk : blk - 64;
  const int role = lb >> 5, u = lb & 31;
  const unsigned epoch = g_epoch;

  { float* Cl = (float*)(smem + CL_OFF); for (int i = tid; i < 512; i += 256) Cl[i] = 0.f; }

  u16* s1 = (u16*)(smem + SEG1_OFF);
  u16* s2 = (u16*)(smem + SEG2_OFF);
  if (encdom) {
    if (role == 0) {
      stage_seg(s1, gb_enc_Whh, 512, 0, u, tid);
    } else {
      stage_seg(s1, gb_enc_Wih + 1048576, 512, 0, u, tid);
      stage_seg(s2, gb_enc_Whh + 1048576, 512, 0, u, tid);
    }
  } else {
    if (role == 0) {
      stage_seg(s1, gb_dec_Wih0, 1024, 512, u, tid);
      stage_seg(s2, gb_dec_Whh, 512, 0, u, tid);
    } else {
      stage_seg(s1, gb_dec_Wih1, 512, 0, u, tid);
      stage_seg(s2, gb_dec_Whh + 1048576, 512, 0, u, tid);
    }
  }
  __syncthreads();

  unsigned* flags = encdom ? g_flags_enc : g_flags_dec;
  unsigned* acks  = encdom ? g_acks_enc  : g_acks_dec;
  unsigned g = sc_ld_u32(encdom ? &g_gen0_enc : &g_gen0_dec);

  if (encdom) {
    for (int s = 0; s < 5; s++) {
      for (int t = 0; t < 32; t++) {
        const int gstep = s * 32 + t, si = gstep & 1, so = si ^ 1;
        if (role == 0)
          lstm_llc(smem, u, lane, wave, tid,
            g_epre + (size_t)gstep * 65536, nullptr,
            g_Henc + (si * 2 + 0) * 16384, nullptr,
            g_Henc + (so * 2 + 0) * 16384, nullptr, 0, t, false);
        bar_dom(flags, acks, lb, tid, g);
        if (role == 1)
          lstm_llc(smem, u, lane, wave, tid,
            nullptr, gc_enc_bias + 2048,
            g_Henc + (so * 2 + 0) * 16384, g_Henc + (si * 2 + 1) * 16384,
            g_Henc + (so * 2 + 1) * 16384, g_encraw5 + (size_t)s * 524288, 2, t, false);
        bar_dom(flags, acks, lb, tid, g);
      }
      // ---- enc LayerNorm: 1024 rows over 64 blocks (16 rows each) ----
      {
        const u16* in = g_encraw5 + (size_t)s * 524288;    // sc-written, first-touch
        u16* out = g_encouts5 + (size_t)s * 524288;
#pragma unroll
        for (int rr = 0; rr < 4; rr++) {
          int row = lb * 16 + wave * 4 + rr;
          const u16* x = in + row * 512 + lane * 8;
          float xs[8]; float sm = 0.f, sq = 0.f;
#pragma unroll
          for (int j = 0; j < 8; j++) { xs[j] = b2f(x[j]); sm += xs[j]; sq += xs[j] * xs[j]; }
#pragma unroll
          for (int off = 32; off; off >>= 1) { sm += __shfl_xor(sm, off, 64); sq += __shfl_xor(sq, off, 64); }
          float mean = sm * (1.f / 512.f);
          float var = fmaxf(sq * (1.f / 512.f) - mean * mean, 0.f);
          float rstd = rsqrtf(var + 1e-5f);
          union { u32x4 v; u16 o[8]; } pk;
#pragma unroll
          for (int j = 0; j < 8; j++) {
            int k = lane * 8 + j;
            pk.o[j] = f2b((xs[j] - mean) * rstd * gc_enc_ln_g[k] + gc_enc_ln_b[k]);
          }
          sc_st16(out + row * 512 + lane * 8, pk.v);
        }
      }
      bar_dom(flags, acks, lb, tid, g);
      // ---- encpart[b][t][h] = enc_outs . att_W[:,512:] + att_b ----
      {
        const u16* eo = g_encouts5 + (size_t)s * 524288;   // sc-written, first-touch
        u16* ep = g_encpart5 + (size_t)s * 524288;
        const int n = lane & 15, q = lane >> 4;
        int rc = lb >> 3, cc = lb & 7;
        int nbase = cc * 64 + wave * 16;
        float bv = gc_att_b[nbase + n];
#pragma unroll
        for (int mt = 0; mt < 4; mt++) {
          int rowbase = rc * 128 + mt * 32;
          f4 bi = { bv, bv, bv, bv };
          Acc2 acc; acc.lo = bi; acc.hi = bi;
          mm_seg(acc, eo + rowbase * 512, gb_att_W + nbase * 1024 + 512, 1024, 512, lane);
#pragma unroll
          for (int r = 0; r < 4; r++) {
            int row = rowbase + q * 4 + r;
            sc_st_u16(ep + row * 512 + nbase + n, f2b(acc.lo[r]));
            sc_st_u16(ep + (row + 16) * 512 + nbase + n, f2b(acc.hi[r]));
          }
        }
      }
      bar_dom(flags, acks, lb, tid, g);
      if (lb == 0 && tid == 0) sc_st_u32(&g_encdone, epoch * 8u + (unsigned)s + 1u);
    }
    if (lb == 0 && tid == 0) sc_st_u32(&g_gen0_enc, g);
  } else {
    for (int s = 0; s < 6; s++) {
      if (s >= 1) {
        if (tid == 0) {
          unsigned tgt = epoch * 8u + (unsigned)s;
          int it = 0;
          while ((int)(sc_ld_u32(&g_encdone) - tgt) < 0 && ++it < SPIN_CAP)
            __builtin_amdgcn_s_sleep(8);
        }
        __syncthreads();
      }
      for (int t = 0; t < 32; t++) {
        const int gstep = s * 32 + t, si = gstep & 1, so = si ^ 1;
        // P1: attention (role 0, s>0)
        if (role == 0 && s > 0) att_llc(smem, u, s, lane, wave, tid);
        bar_dom(flags, acks, lb, tid, g);
        // P2: dec L0 (role 0)
        if (role == 0)
          lstm_llc(smem, u, lane, wave, tid,
            g_dpre + (size_t)gstep * 65536, nullptr,
            (s > 0) ? g_ctx : nullptr, g_Hdec + (si * 2 + 0) * 16384,
            g_Hdec + (so * 2 + 0) * 16384, nullptr, 0, t, false);
        bar_dom(flags, acks, lb, tid, g);
        // P3: dec L1 (role 1) + pqp
        if (role == 1) {
          int dp = ((s > 0 && t < 31) || (t == 31 && s < 5)) ? 1 : 0;
          u16* outp = (s >= 1) ? (g_outsb5 + (size_t)(s - 1) * 524288) : nullptr;
          lstm_llc(smem, u, lane, wave, tid,
            nullptr, gc_dec_bias + 2048,
            g_Hdec + (so * 2 + 0) * 16384, g_Hdec + (si * 2 + 1) * 16384,
            g_Hdec + (so * 2 + 1) * 16384, outp, outp ? 1 : 0, t, dp != 0);
        }
        bar_dom(flags, acks, lb, tid, g);
      }
    }
    if (lb == 0 && tid == 0) sc_st_u32(&g_gen0_dec, g);
  }
}

// ---- deferred decoder LayerNorm over all 5 sentences (5120 rows) ------------
__global__ void __launch_bounds__(256) k_ln_post(Params P)
{
  const int blk = blockIdx.x, tid = threadIdx.x;
  const int lane = tid & 63, wave = tid >> 6;
#pragma unroll
  for (int rr = 0; rr < 2; rr++) {
    int row = blk * 8 + wave * 2 + rr;                    // 0..5119
    const u16* x = g_outsb5 + (size_t)row * 512 + lane * 8;
    float xs[8]; float sm = 0.f, sq = 0.f;
#pragma unroll
    for (int j = 0; j < 8; j++) { xs[j] = b2f(x[j]); sm += xs[j]; sq += xs[j] * xs[j]; }
#pragma unroll
    for (int off = 32; off; off >>= 1) { sm += __shfl_xor(sm, off, 64); sq += __shfl_xor(sq, off, 64); }
    float mean = sm * (1.f / 512.f);
    float var = fmaxf(sq * (1.f / 512.f) - mean * mean, 0.f);
    float rstd = rsqrtf(var + 1e-5f);
    u16* o = g_lnouts5 + (size_t)row * 512 + lane * 8;
#pragma unroll
    for (int j = 0; j < 8; j++) {
      int k = lane * 8 + j;
      o[j] = f2b((xs[j] - mean) * rstd * gc_dec_ln_g[k] + gc_dec_ln_b[k]);
    }
  }
}

// ---- deferred FC over all 5 sentences: logits -> out[b][s-1][t][v] ----------
__global__ void __launch_bounds__(256) k_fc_post(Params P)
{
  __shared__ char sbuf[65536];
  const int blk0 = blockIdx.x, tid = threadIdx.x;
  const int sidx = blk0 / 192, blk = blk0 % 192;
  const int lane = tid & 63, wave = tid >> 6;
  const int n = lane & 15, q = lane >> 4;
  const bool f32o = is_f32(P);
  const u16* lnin = g_lnouts5 + (size_t)sidx * 524288;
  u16* As = (u16*)sbuf;                  // [64 rows][512], XOR-swizzled 16B chunks
  int mc = blk / 12, ncc = blk % 12;
  int mrow0 = mc * 64;
  for (int idx = tid; idx < 64 * 64; idx += 256) {
    int row = idx >> 6, ch = idx & 63;
    int phys = ch ^ (row & 7);
    *(u32x4*)(As + (row * 64 + phys) * 8) = *(const u32x4*)(lnin + (size_t)(mrow0 + row) * 512 + ch * 8);
  }
  __syncthreads();
  f4 acc[4][8];
#pragma unroll
  for (int j = 0; j < 8; j++) {
    int c = ncc * 512 + wave * 128 + j * 16 + n;
    float bv = (c < 6000) ? gc_fc_b[c] : 0.f;
    f4 bi = { bv, bv, bv, bv };
#pragma unroll
    for (int mt = 0; mt < 4; mt++) acc[mt][j] = bi;
  }
  for (int kt = 0; kt < 16; kt++) {
    bf8 a[4];
#pragma unroll
    for (int mt = 0; mt < 4; mt++) {
      int row = mt * 16 + n;
      int ch = kt * 4 + q;
      int phys = ch ^ (row & 7);
      a[mt] = *(const bf8*)(As + (row * 64 + phys) * 8);
    }
#pragma unroll
    for (int j = 0; j < 8; j++) {
      int c = ncc * 512 + wave * 128 + j * 16 + n;
      int brow = (c < 6000) ? c : 5999;
      bf8 vb = *(const bf8*)(gb_fc_W + brow * 512 + kt * 32 + q * 8);
#pragma unroll
      for (int mt = 0; mt < 4; mt++)
        acc[mt][j] = __builtin_amdgcn_mfma_f32_16x16x32_bf16(a[mt], vb, acc[mt][j], 0, 0, 0);
    }
  }
#pragma unroll
  for (int j = 0; j < 8; j++) {
    int c = ncc * 512 + wave * 128 + j * 16 + n;
    if (c < 6000) {
#pragma unroll
      for (int mt = 0; mt < 4; mt++) {
#pragma unroll
        for (int r = 0; r < 4; r++) {
          int rix = mrow0 + mt * 16 + q * 4 + r;   // row = t*32 + b
          int tt = rix >> 5, b = rix & 31;
          size_t oidx = (size_t)((b * 5 + sidx) * 32 + tt) * 6000 + c;
          float v = acc[mt][j][r];
          if (f32o) ((float*)P.out)[oidx] = v;
          else      ((u16*)P.out)[oidx] = f2b(v);
        }
      }
    }
  }
}

extern "C" void kernel_launch(void* const* d_in, const int* in_sizes, int n_in,
                              void* d_out, int out_size, void* d_ws, size_t ws_size,
                              hipStream_t stream) {
  Params P;
  P.inputs   = (const int*)d_in[0];
  P.targets  = (const int*)d_in[1];
  P.enc_emb  = d_in[2];
  P.enc_Wih  = d_in[3];
  P.enc_Whh  = d_in[4];
  P.enc_bias = d_in[5];
  P.enc_ln_g = d_in[6];
  P.enc_ln_b = d_in[7];
  P.dec_emb  = d_in[8];
  P.att_W    = d_in[9];
  P.att_b    = d_in[10];
  P.att_v    = d_in[11];
  P.dec_Wih0 = d_in[12];
  P.dec_Wih1 = d_in[13];
  P.dec_Whh  = d_in[14];
  P.dec_bias = d_in[15];
  P.dec_ln_g = d_in[16];
  P.dec_ln_b = d_in[17];
  P.fc_W     = d_in[18];
  P.fc_b     = d_in[19];
  P.out = d_out;

  static bool attr_done = false;
  if (!attr_done) {
    hipFuncSetAttribute((const void*)k_persist,
                        hipFuncAttributeMaxDynamicSharedMemorySize, LDS_TOTAL);
    attr_done = true;
  }

  hipLaunchKernelGGL(k_conv, dim3(9364), dim3(256), 0, stream, P);
  hipLaunchKernelGGL(k_conv_small, dim3(68), dim3(256), 0, stream, P);
  hipLaunchKernelGGL(k_setup, dim3(256), dim3(256), 0, stream, P);
  hipLaunchKernelGGL(k_pre, dim3(2816), dim3(256), 0, stream);
  hipLaunchKernelGGL(k_persist, dim3(128), dim3(256), LDS_TOTAL, stream);
  hipLaunchKernelGGL(k_ln_post, dim3(640), dim3(256), 0, stream, P);
  hipLaunchKernelGGL(k_fc_post, dim3(960), dim3(256), 0, stream, P);
}

// Round 9
// 11508.810 us; speedup vs baseline: 1.4827x; 1.0911x over previous
//
#include <hip/hip_runtime.h>

typedef unsigned short u16;
typedef __attribute__((ext_vector_type(8))) short bf8;     // 8 x bf16 (4 VGPRs)
typedef __attribute__((ext_vector_type(4))) float f4;      // MFMA C/D frag
typedef __attribute__((ext_vector_type(4))) unsigned int u32x4;

struct Params {
  const int* inputs; const int* targets;
  const void *enc_emb, *enc_Wih, *enc_Whh, *enc_bias, *enc_ln_g, *enc_ln_b;
  const void *dec_emb, *att_W, *att_b, *att_v;
  const void *dec_Wih0, *dec_Wih1, *dec_Whh, *dec_bias, *dec_ln_g, *dec_ln_b;
  const void *fc_W, *fc_b;
  void* out;
};

// -------- canonical weight/vector buffers (filled by k_conv each launch) -----
__device__ __align__(16) u16 gb_enc_emb[3072000];
__device__ __align__(16) u16 gb_dec_emb[3072000];
__device__ __align__(16) u16 gb_enc_Wih[2097152];
__device__ __align__(16) u16 gb_enc_Whh[2097152];
__device__ __align__(16) u16 gb_dec_Wih0[2097152];
__device__ __align__(16) u16 gb_dec_Wih1[1048576];
__device__ __align__(16) u16 gb_dec_Whh[2097152];
__device__ __align__(16) u16 gb_att_W[524288];
__device__ __align__(16) u16 gb_fc_W[3072000];
__device__ float gc_enc_bias[4096], gc_dec_bias[4096];
__device__ float gc_enc_ln_g[512], gc_enc_ln_b[512], gc_dec_ln_g[512], gc_dec_ln_b[512];
__device__ float gc_att_b[512], gc_att_v[512], gc_fc_b[6000];

// ---------------- state scratch in device globals ----------------------------
__device__ __align__(16) u16 g_Hdec[4 * 32 * 512];       // [slot][layer][b][h]
__device__ __align__(16) u16 g_Henc[4 * 32 * 512];
__device__ __align__(16) u16 g_ctx[32 * 512];
__device__ __align__(16) u16 g_outsb5[5 * 1024 * 512];   // [s-1][t*32+b][h]
__device__ __align__(16) u16 g_lnouts5[5 * 1024 * 512];
__device__ __align__(16) u16 g_encraw5[5 * 1024 * 512];  // [s][b*32+t][h]
__device__ __align__(16) u16 g_encouts5[5 * 1024 * 512]; // [s][b*32+t][h]
__device__ __align__(16) u16 g_encpart5[5 * 1024 * 512];
__device__ int g_masks[6 * 32 * 32];
__device__ int g_dtoks[6 * 32 * 32];                     // [s][t][b]
__device__ int g_etoks[5 * 32 * 32];

// precomputed emb-input gate partials (bias folded in), layout [gstep][c 2048][b 32] f32
__device__ __align__(16) float g_dpre[192 * 2048 * 32];
__device__ __align__(16) float g_epre[160 * 2048 * 32];

// ---------------- barrier state (zero-init; monotonic across launches) -------
__device__ unsigned g_flags_enc[64 * 32], g_acks_enc[64 * 32];
__device__ unsigned g_flags_dec[64 * 32], g_acks_dec[64 * 32];
__device__ unsigned g_gen0_enc, g_gen0_dec, g_encdone, g_epoch;

// LDS layout for k_persist (dynamic shared)
#define GL_OFF   0          // gate exchange: 4*32*17*4 = 8704 B (also att scratch)
#define HL_OFF   8704       // (spare) 2048 B
#define CL_OFF   10752      // C state f32: 32*16*4 = 2048 B (block-private)
#define SEG1_OFF 12800      // weight seg 1: 4 waves * 16 rows * 512 u16 = 65536 B
#define SEG2_OFF 78336      // weight seg 2: 65536 B
#define LDS_TOTAL 143872

#define SPIN_CAP (1 << 27)   // deadlock -> wrong-answer safety valve (~seconds)

__device__ __forceinline__ float b2f(u16 u) { union { unsigned i; float f; } v; v.i = ((unsigned)u) << 16; return v.f; }
__device__ __forceinline__ u16 f2b(float f) {
  union { float f; unsigned i; } v; v.f = f;
  unsigned x = v.i;
  return (u16)((x + 0x7fffu + ((x >> 16) & 1u)) >> 16);    // RNE
}
__device__ __forceinline__ float sigf(float x) { return 1.f / (1.f + __expf(-x)); }
__device__ __forceinline__ float tanhf_(float x) { float e = __expf(2.f * x); return 1.f - 2.f / (e + 1.f); }

__device__ __forceinline__ bool is_f32(const Params& P) {
  return *(const unsigned*)P.enc_ln_g == 0x3F800000u;
}

// ---------------- LLC-coherent (sc0 sc1) access helpers ----------------------
#define VWAIT(N) do { asm volatile("s_waitcnt vmcnt(" #N ")" ::: "memory"); \
                      __builtin_amdgcn_sched_barrier(0); } while (0)

__device__ __forceinline__ void sc_ld(bf8& d, const u16* p) {
  asm volatile("global_load_dwordx4 %0, %1, off sc0 sc1" : "=v"(d) : "v"(p));
}
__device__ __forceinline__ void sc_st16(u16* p, u32x4 v) {
  asm volatile("global_store_dwordx4 %0, %1, off sc0 sc1" :: "v"(p), "v"(v) : "memory");
}
__device__ __forceinline__ void sc_st_u16(u16* p, u16 v) {
  unsigned vv = v;
  asm volatile("global_store_short %0, %1, off sc0 sc1" :: "v"(p), "v"(vv) : "memory");
}
__device__ __forceinline__ unsigned sc_ld_u32(const unsigned* p) {
  unsigned r;
  asm volatile("global_load_dword %0, %1, off sc0 sc1\n\ts_waitcnt vmcnt(0)"
               : "=v"(r) : "v"(p) : "memory");
  return r;
}
__device__ __forceinline__ void sc_st_u32(unsigned* p, unsigned v) {
  asm volatile("global_store_dword %0, %1, off sc0 sc1\n\ts_waitcnt vmcnt(0)"
               :: "v"(p), "v"(v) : "memory");
}

// ---------------- fence-free domain barrier (64 blocks) -----------------------
// Every wave drains its own VMEM (vmcnt(0)) before s_barrier; arrival flag is an
// sc store; leader lanes each poll ONE follower flag then ack on the follower's
// private line. No cache invalidation anywhere. Spins are capped so a protocol
// bug shows as wrong-answer (with counters), not an opaque hang.
__device__ __forceinline__ void bar_dom(unsigned* flags, unsigned* acks, int lb, int tid, unsigned& g) {
  g += 1;
  asm volatile("s_waitcnt vmcnt(0)" ::: "memory");
  __syncthreads();
  if (lb == 0) {
    if (tid >= 1 && tid < 64) {
      int it = 0;
      while (sc_ld_u32(flags + tid * 32) != g && ++it < SPIN_CAP) __builtin_amdgcn_s_sleep(2);
      sc_st_u32(acks + tid * 32, g);
    }
    __syncthreads();
  } else {
    if (tid == 0) {
      sc_st_u32(flags + lb * 32, g);
      int it = 0;
      while (sc_ld_u32(acks + lb * 32) != g && ++it < SPIN_CAP) __builtin_amdgcn_s_sleep(2);
    }
    __syncthreads();
  }
}

struct Acc2 { f4 lo, hi; };

// C[0:32,0:16] += A[0:32,0:K] * Wp[0:16,0:K]^T (normal cached loads; immutable A/W)
__device__ __forceinline__ void mm_seg(Acc2& a, const u16* A, const u16* Wp, int ldW, int K, int lane) {
  const int n = lane & 15, q = lane >> 4;
  const u16* a0 = A + n * 512 + q * 8;
  const u16* a1 = a0 + 16 * 512;
  const u16* bp = Wp + n * ldW + q * 8;
  for (int k = 0; k < K; k += 32) {
    bf8 va0 = *(const bf8*)(a0 + k);
    bf8 va1 = *(const bf8*)(a1 + k);
    bf8 vb  = *(const bf8*)(bp + k);
    a.lo = __builtin_amdgcn_mfma_f32_16x16x32_bf16(va0, vb, a.lo, 0, 0, 0);
    a.hi = __builtin_amdgcn_mfma_f32_16x16x32_bf16(va1, vb, a.hi, 0, 0, 0);
  }
}

// A rows gathered from an embedding table by token id (K = 512, normal loads)
__device__ __forceinline__ void mm_tok(Acc2& a, const u16* emb, const int* toks,
                                       const u16* Wp, int ldW, int lane) {
  const int n = lane & 15, q = lane >> 4;
  const u16* a0 = emb + (size_t)toks[n] * 512 + q * 8;
  const u16* a1 = emb + (size_t)toks[n + 16] * 512 + q * 8;
  const u16* bp = Wp + n * ldW + q * 8;
  for (int k = 0; k < 512; k += 32) {
    bf8 va0 = *(const bf8*)(a0 + k);
    bf8 va1 = *(const bf8*)(a1 + k);
    bf8 vb  = *(const bf8*)(bp + k);
    a.lo = __builtin_amdgcn_mfma_f32_16x16x32_bf16(va0, vb, a.lo, 0, 0, 0);
    a.hi = __builtin_amdgcn_mfma_f32_16x16x32_bf16(va1, vb, a.hi, 0, 0, 0);
  }
}

// A[32][512] via coherent sc loads (all 32 issued upfront, descending counted
// vmcnt ladder -> one LLC latency per GEMM), W from LDS (XOR-swizzled)
__device__ __forceinline__ void mm_seg_llc(Acc2& a, const u16* A, const u16* Wl, int lane) {
  const int n = lane & 15, q = lane >> 4, x = n & 7;
  const u16* a0 = A + n * 512 + q * 8;
  const u16* a1 = a0 + 8192;                 // row n+16
  const u16* wr = Wl + n * 512;
  bf8 r0[4][4], r1[4][4];
#pragma unroll
  for (int c = 0; c < 4; c++)
#pragma unroll
    for (int j = 0; j < 4; j++) {
      sc_ld(r0[c][j], a0 + c * 128 + j * 32);
      sc_ld(r1[c][j], a1 + c * 128 + j * 32);
    }
#pragma unroll
  for (int c = 0; c < 4; c++) {
    if (c == 0) VWAIT(24); else if (c == 1) VWAIT(16); else if (c == 2) VWAIT(8); else VWAIT(0);
#pragma unroll
    for (int j = 0; j < 4; j++) {
      int ki = c * 4 + j;
      bf8 vb = *(const bf8*)(wr + (((q + 4 * ki) ^ x) << 3));
      a.lo = __builtin_amdgcn_mfma_f32_16x16x32_bf16(r0[c][j], vb, a.lo, 0, 0, 0);
      a.hi = __builtin_amdgcn_mfma_f32_16x16x32_bf16(r1[c][j], vb, a.hi, 0, 0, 0);
    }
  }
}

// stage a 64KB weight slice (4 waves x 16 rows x 512 cols) into LDS, swizzled
__device__ __forceinline__ void stage_seg(u16* lds_seg, const u16* W, int ldW, int c0, int u, int tid) {
  for (int idx = tid; idx < 4096; idx += 256) {
    int w = idx >> 10, n = (idx >> 6) & 15, ch = idx & 63;
    const u16* src = W + (size_t)(w * 512 + u * 16 + n) * ldW + c0 + ch * 8;
    u16* dst = lds_seg + ((w * 16 + n) * 64 + (ch ^ (n & 7))) * 8;
    *(u32x4*)dst = *(const u32x4*)src;
  }
}

// One LSTM layer step: weights in LDS, A via sc loads, C in LDS, H out via sc.
__device__ __forceinline__ void lstm_llc(char* smem, int u, int lane, int wave, int tid,
    const float* pre, const float* bias,
    const u16* A1, const u16* A2,
    u16* Hout, u16* Xtra, int xmode, int t)
{
  float* gl = (float*)(smem + GL_OFF);             // [4][32][17]
  float* Cl = (float*)(smem + CL_OFF);             // [32][16]
  const u16* seg1 = (const u16*)(smem + SEG1_OFF) + wave * 8192;
  const u16* seg2 = (const u16*)(smem + SEG2_OFF) + wave * 8192;
  const int n = lane & 15, q = lane >> 4;
  const int colbase = wave * 512 + u * 16;
  Acc2 acc;
  if (pre) {
    const float* pb = pre + (size_t)(colbase + n) * 32;
    acc.lo = *(const f4*)(pb + q * 4);
    acc.hi = *(const f4*)(pb + q * 4 + 16);
  } else {
    float bv = bias[colbase + n];
    f4 bi = { bv, bv, bv, bv };
    acc.lo = bi; acc.hi = bi;
  }
  if (A1) mm_seg_llc(acc, A1, seg1, lane);
  if (A2) mm_seg_llc(acc, A2, seg2, lane);
#pragma unroll
  for (int r = 0; r < 4; r++) {
    gl[(wave * 32 + q * 4 + r) * 17 + n]      = acc.lo[r];
    gl[(wave * 32 + 16 + q * 4 + r) * 17 + n] = acc.hi[r];
  }
  __syncthreads();
  for (int p = tid; p < 512; p += 256) {
    int b = p >> 4, nn = p & 15, hc = u * 16 + nn;
    float iv = gl[(0 * 32 + b) * 17 + nn];
    float fv = gl[(1 * 32 + b) * 17 + nn];
    float gv = gl[(2 * 32 + b) * 17 + nn];
    float ov = gl[(3 * 32 + b) * 17 + nn];
    float c2 = sigf(fv) * Cl[b * 16 + nn] + sigf(iv) * tanhf_(gv);
    float h2 = sigf(ov) * tanhf_(c2);
    Cl[b * 16 + nn] = c2;
    u16 hb = f2b(h2);
    sc_st_u16(Hout + b * 512 + hc, hb);
    if (xmode == 1)      Xtra[(t * 32 + b) * 512 + hc] = hb;          // outsb5 (normal)
    else if (xmode == 2) sc_st_u16(Xtra + (b * 32 + t) * 512 + hc, hb); // encraw (sc)
  }
}

// attention for batch row b (one block), result -> g_ctx[b][:] (sc).
// qp = h1[b,:] @ attW[:, :512]^T computed HERE from L2-resident attW (no pqp
// global round-trip; h1 read via sc, 1 KB).
__device__ __forceinline__ void att_llc(char* smem, int b, int s, int si, int lane, int wave, int tid)
{
  float* qp  = (float*)(smem + GL_OFF);
  float* sc  = qp + 512;
  float* av  = sc + 32;
  float* hlf = av + 32;                                  // [512] f32
  const u16* ep_prev = g_encpart5 + (size_t)(s - 1) * 524288;
  const u16* eo_prev = g_encouts5 + (size_t)(s - 1) * 524288;
  const u16* h1 = g_Hdec + (si * 2 + 1) * 16384 + b * 512;

  if (wave == 0) {                                       // load h1 -> LDS f32
    bf8 v; sc_ld(v, h1 + lane * 8);
    VWAIT(0);
#pragma unroll
    for (int j = 0; j < 8; j++) hlf[lane * 8 + j] = b2f((u16)v[j]);
  }
  __syncthreads();
  for (int h = tid; h < 512; h += 256) {
    const u16* wrow = gb_att_W + (size_t)h * 1024;       // first 512 cols
    float acc = 0.f;
#pragma unroll 8
    for (int kk = 0; kk < 64; kk++) {
      bf8 w = *(const bf8*)(wrow + kk * 8);
#pragma unroll
      for (int j = 0; j < 8; j++) acc += hlf[kk * 8 + j] * b2f((u16)w[j]);
    }
    qp[h] = acc;
  }
  __syncthreads();
  for (int tt = wave; tt < 32; tt += 4) {
    float part = 0.f;
    for (int h = lane; h < 512; h += 64)
      part += tanhf_(qp[h] + b2f(ep_prev[(b * 32 + tt) * 512 + h])) * gc_att_v[h];
#pragma unroll
    for (int off = 32; off; off >>= 1) part += __shfl_xor(part, off, 64);
    if (lane == 0) sc[tt] = g_masks[(s * 32 + b) * 32 + tt] ? -1e9f : fminf(fmaxf(part, -1e30f), 1e30f);
  }
  __syncthreads();
  if (wave == 0) {
    float v = (lane < 32) ? sc[lane] : -3e38f;
    float m = v;
#pragma unroll
    for (int off = 32; off; off >>= 1) m = fmaxf(m, __shfl_xor(m, off, 64));
    float e = (lane < 32) ? __expf(v - m) : 0.f;
    float ssum = e;
#pragma unroll
    for (int off = 32; off; off >>= 1) ssum += __shfl_xor(ssum, off, 64);
    if (lane < 32) av[lane] = e / ssum;
  }
  __syncthreads();
  for (int h = tid; h < 512; h += 256) {
    float ssum = 0.f;
#pragma unroll 4
    for (int tt = 0; tt < 32; tt++) ssum += av[tt] * b2f(eo_prev[(b * 32 + tt) * 512 + h]);
    sc_st_u16(g_ctx + b * 512 + h, f2b(ssum));
  }
}

// ---------------------------- kernels ----------------------------------------

__global__ void __launch_bounds__(256) k_conv(Params P)
{
  const bool f32 = is_f32(P);
  int c = blockIdx.x * 256 + threadIdx.x;    // chunk of 8 elements
  const void* src; u16* dst;
  if (c < 384000)                 { src = P.enc_emb;  dst = gb_enc_emb;  }
  else if ((c -= 384000) < 384000){ src = P.dec_emb;  dst = gb_dec_emb;  }
  else if ((c -= 384000) < 262144){ src = P.enc_Wih;  dst = gb_enc_Wih;  }
  else if ((c -= 262144) < 262144){ src = P.enc_Whh;  dst = gb_enc_Whh;  }
  else if ((c -= 262144) < 262144){ src = P.dec_Wih0; dst = gb_dec_Wih0; }
  else if ((c -= 262144) < 131072){ src = P.dec_Wih1; dst = gb_dec_Wih1; }
  else if ((c -= 131072) < 262144){ src = P.dec_Whh;  dst = gb_dec_Whh;  }
  else if ((c -= 262144) < 65536) { src = P.att_W;    dst = gb_att_W;    }
  else                            { c -= 65536; src = P.fc_W; dst = gb_fc_W; }
  if (f32) {
    const float* s = (const float*)src + (size_t)c * 8;
    union { u32x4 v; u16 o[8]; } u;
#pragma unroll
    for (int j = 0; j < 8; j++) u.o[j] = f2b(s[j]);
    *(u32x4*)(dst + (size_t)c * 8) = u.v;
  } else {
    ((u32x4*)dst)[c] = ((const u32x4*)src)[c];
  }
}

__global__ void __launch_bounds__(256) k_conv_small(Params P)
{
  const bool f32 = is_f32(P);
  int i = blockIdx.x * 256 + threadIdx.x;
  const void* src; float* dst;
  if (i < 4096)                 { src = P.enc_bias; dst = gc_enc_bias; }
  else if ((i -= 4096) < 4096)  { src = P.dec_bias; dst = gc_dec_bias; }
  else if ((i -= 4096) < 512)   { src = P.enc_ln_g; dst = gc_enc_ln_g; }
  else if ((i -= 512) < 512)    { src = P.enc_ln_b; dst = gc_enc_ln_b; }
  else if ((i -= 512) < 512)    { src = P.dec_ln_g; dst = gc_dec_ln_g; }
  else if ((i -= 512) < 512)    { src = P.dec_ln_b; dst = gc_dec_ln_b; }
  else if ((i -= 512) < 512)    { src = P.att_b;    dst = gc_att_b;    }
  else if ((i -= 512) < 512)    { src = P.att_v;    dst = gc_att_v;    }
  else if ((i -= 512) < 6000)   { src = P.fc_b;     dst = gc_fc_b;     }
  else return;
  dst[i] = f32 ? ((const float*)src)[i] : b2f(((const u16*)src)[i]);
}

__global__ void __launch_bounds__(256) k_setup(Params P)
{
  const int gtid = blockIdx.x * 256 + threadIdx.x;
  if (gtid == 0) g_epoch = g_epoch + 1;
  if (gtid < 6144) {                      // dtoks[s][t][b]
    int s = gtid >> 10, rem = gtid & 1023, t = rem >> 5, b = rem & 31;
    int tok = (t == 0) ? 1
            : ((s == 0) ? P.inputs[b * 192 + (t - 1)] : P.targets[b * 160 + (s - 1) * 32 + (t - 1)]);
    g_dtoks[gtid] = tok;
  } else if (gtid < 6144 + 5120) {        // etoks[s][t][b]
    int gi = gtid - 6144;
    int s = gi >> 10, rem = gi & 1023, t = rem >> 5, b = rem & 31;
    g_etoks[gi] = (s == 0) ? P.inputs[b * 192 + t] : P.targets[b * 160 + (s - 1) * 32 + t];
  }
  if (blockIdx.x >= 64 && blockIdx.x < 224 && threadIdx.x == 0) {  // masks[s][b][t]
    int w = blockIdx.x - 64;
    int s = 1 + (w >> 5), b = w & 31;
    int seen = 0;
    g_masks[(s * 32 + b) * 32 + 0] = 0;
    for (int t2 = 1; t2 < 32; t2++) {
      int tk = (s == 1) ? P.inputs[b * 192 + (t2 - 1)] : P.targets[b * 160 + (s - 2) * 32 + (t2 - 1)];
      seen |= (tk == 2 || tk == 3) ? 1 : 0;
      g_masks[(s * 32 + b) * 32 + t2] = seen;
    }
  }
  u32x4 z = { 0u, 0u, 0u, 0u };
  if (gtid < 8192)  ((u32x4*)g_Hdec)[gtid] = z;
  if (gtid >= 8192 && gtid < 16384) ((u32x4*)g_Henc)[gtid - 8192] = z;
  if (gtid >= 16384 && gtid < 18432) ((u32x4*)g_ctx)[gtid - 16384] = z;
}

// precompute emb-input gate partials for all timesteps
__global__ void __launch_bounds__(256) k_pre()
{
  const int blk = blockIdx.x, tid = threadIdx.x;
  const int lane = tid & 63, wave = tid >> 6;
  const int n = lane & 15, q = lane >> 4;
  const bool dec = blk < 1536;
  const int idx = dec ? blk : blk - 1536;
  const int u = idx & 31, gq = idx >> 5;
  const u16* emb = dec ? gb_dec_emb : gb_enc_emb;
  const u16* W   = dec ? gb_dec_Wih0 : gb_enc_Wih;
  const int ldW  = dec ? 1024 : 512;
  const float* bias = dec ? gc_dec_bias : gc_enc_bias;
  float* pre = dec ? g_dpre : g_epre;
  const int* toks = dec ? g_dtoks : g_etoks;
  const int colbase = wave * 512 + u * 16;
  for (int gi = 0; gi < 4; gi++) {
    int gstep = gq * 4 + gi;
    float bv = bias[colbase + n];
    f4 bi = { bv, bv, bv, bv };
    Acc2 acc; acc.lo = bi; acc.hi = bi;
    mm_tok(acc, emb, toks + gstep * 32, W + (size_t)colbase * ldW, ldW, lane);
    float* dst = pre + ((size_t)gstep * 2048 + colbase + n) * 32;
    *(f4*)(dst + q * 4) = acc.lo;
    *(f4*)(dst + q * 4 + 16) = acc.hi;
  }
}

// ---------------- the persistent recurrence kernel ---------------------------
// 128 blocks, 1/CU. Two independent barrier domains:
//   enc = blocks 0-63  (role 0: enc L0, role 1: enc L1), 2 phases/step
//   dec = blocks 64-127 (role 0: att+dec L0, role 1: dec L1), 3 phases/step
// enc runs ahead; dec waits on a per-sentence enc_done flag. No cache fences:
// all racy state moves via sc0 sc1 (LLC) accesses; read-only data stays L2-hot.
__global__ void __launch_bounds__(256) k_persist()
{
  extern __shared__ char smem[];
  const int blk = blockIdx.x, tid = threadIdx.x;
  const int lane = tid & 63, wave = tid >> 6;
  const bool encdom = blk < 64;
  const int lb = encdom ? blk : blk - 64;
  const int role = lb >> 5, u = lb & 31;
  const unsigned epoch = g_epoch;

  { float* Cl = (float*)(smem + CL_OFF); for (int i = tid; i < 512; i += 256) Cl[i] = 0.f; }

  u16* s1 = (u16*)(smem + SEG1_OFF);
  u16* s2 = (u16*)(smem + SEG2_OFF);
  if (encdom) {
    if (role == 0) {
      stage_seg(s1, gb_enc_Whh, 512, 0, u, tid);
    } else {
      stage_seg(s1, gb_enc_Wih + 1048576, 512, 0, u, tid);
      stage_seg(s2, gb_enc_Whh + 1048576, 512, 0, u, tid);
    }
  } else {
    if (role == 0) {
      stage_seg(s1, gb_dec_Wih0, 1024, 512, u, tid);
      stage_seg(s2, gb_dec_Whh, 512, 0, u, tid);
    } else {
      stage_seg(s1, gb_dec_Wih1, 512, 0, u, tid);
      stage_seg(s2, gb_dec_Whh + 1048576, 512, 0, u, tid);
    }
  }
  __syncthreads();

  unsigned* flags = encdom ? g_flags_enc : g_flags_dec;
  unsigned* acks  = encdom ? g_acks_enc  : g_acks_dec;
  unsigned g = sc_ld_u32(encdom ? &g_gen0_enc : &g_gen0_dec);

  if (encdom) {
    for (int s = 0; s < 5; s++) {
      for (int t = 0; t < 32; t++) {
        const int gstep = s * 32 + t, si = gstep & 1, so = si ^ 1;
        if (role == 0)
          lstm_llc(smem, u, lane, wave, tid,
            g_epre + (size_t)gstep * 65536, nullptr,
            g_Henc + (si * 2 + 0) * 16384, nullptr,
            g_Henc + (so * 2 + 0) * 16384, nullptr, 0, t);
        bar_dom(flags, acks, lb, tid, g);
        if (role == 1)
          lstm_llc(smem, u, lane, wave, tid,
            nullptr, gc_enc_bias + 2048,
            g_Henc + (so * 2 + 0) * 16384, g_Henc + (si * 2 + 1) * 16384,
            g_Henc + (so * 2 + 1) * 16384, g_encraw5 + (size_t)s * 524288, 2, t);
        bar_dom(flags, acks, lb, tid, g);
      }
      // ---- enc LayerNorm: 1024 rows over 64 blocks (16 rows each) ----
      {
        const u16* in = g_encraw5 + (size_t)s * 524288;    // sc-written, first-touch
        u16* out = g_encouts5 + (size_t)s * 524288;
#pragma unroll
        for (int rr = 0; rr < 4; rr++) {
          int row = lb * 16 + wave * 4 + rr;
          const u16* x = in + row * 512 + lane * 8;
          float xs[8]; float sm = 0.f, sq = 0.f;
#pragma unroll
          for (int j = 0; j < 8; j++) { xs[j] = b2f(x[j]); sm += xs[j]; sq += xs[j] * xs[j]; }
#pragma unroll
          for (int off = 32; off; off >>= 1) { sm += __shfl_xor(sm, off, 64); sq += __shfl_xor(sq, off, 64); }
          float mean = sm * (1.f / 512.f);
          float var = fmaxf(sq * (1.f / 512.f) - mean * mean, 0.f);
          float rstd = rsqrtf(var + 1e-5f);
          union { u32x4 v; u16 o[8]; } pk;
#pragma unroll
          for (int j = 0; j < 8; j++) {
            int k = lane * 8 + j;
            pk.o[j] = f2b((xs[j] - mean) * rstd * gc_enc_ln_g[k] + gc_enc_ln_b[k]);
          }
          sc_st16(out + row * 512 + lane * 8, pk.v);
        }
      }
      bar_dom(flags, acks, lb, tid, g);
      // ---- encpart[b][t][h] = enc_outs . att_W[:,512:] + att_b ----
      {
        const u16* eo = g_encouts5 + (size_t)s * 524288;   // sc-written, first-touch
        u16* ep = g_encpart5 + (size_t)s * 524288;
        const int n = lane & 15, q = lane >> 4;
        int rc = lb >> 3, cc = lb & 7;
        int nbase = cc * 64 + wave * 16;
        float bv = gc_att_b[nbase + n];
#pragma unroll
        for (int mt = 0; mt < 4; mt++) {
          int rowbase = rc * 128 + mt * 32;
          f4 bi = { bv, bv, bv, bv };
          Acc2 acc; acc.lo = bi; acc.hi = bi;
          mm_seg(acc, eo + rowbase * 512, gb_att_W + nbase * 1024 + 512, 1024, 512, lane);
#pragma unroll
          for (int r = 0; r < 4; r++) {
            int row = rowbase + q * 4 + r;
            sc_st_u16(ep + row * 512 + nbase + n, f2b(acc.lo[r]));
            sc_st_u16(ep + (row + 16) * 512 + nbase + n, f2b(acc.hi[r]));
          }
        }
      }
      bar_dom(flags, acks, lb, tid, g);
      if (lb == 0 && tid == 0) sc_st_u32(&g_encdone, epoch * 8u + (unsigned)s + 1u);
    }
    if (lb == 0 && tid == 0) sc_st_u32(&g_gen0_enc, g);
  } else {
    for (int s = 0; s < 6; s++) {
      if (s >= 1) {
        if (tid == 0) {
          unsigned tgt = epoch * 8u + (unsigned)s;
          int it = 0;
          while ((int)(sc_ld_u32(&g_encdone) - tgt) < 0 && ++it < SPIN_CAP)
            __builtin_amdgcn_s_sleep(8);
        }
        __syncthreads();
      }
      for (int t = 0; t < 32; t++) {
        const int gstep = s * 32 + t, si = gstep & 1, so = si ^ 1;
        // P1: attention (role 0, s>0) — h1 prev lives in slot (si*2+1)
        if (role == 0 && s > 0) att_llc(smem, u, s, si, lane, wave, tid);
        bar_dom(flags, acks, lb, tid, g);
        // P2: dec L0 (role 0)
        if (role == 0)
          lstm_llc(smem, u, lane, wave, tid,
            g_dpre + (size_t)gstep * 65536, nullptr,
            (s > 0) ? g_ctx : nullptr, g_Hdec + (si * 2 + 0) * 16384,
            g_Hdec + (so * 2 + 0) * 16384, nullptr, 0, t);
        bar_dom(flags, acks, lb, tid, g);
        // P3: dec L1 (role 1)
        if (role == 1) {
          u16* outp = (s >= 1) ? (g_outsb5 + (size_t)(s - 1) * 524288) : nullptr;
          lstm_llc(smem, u, lane, wave, tid,
            nullptr, gc_dec_bias + 2048,
            g_Hdec + (so * 2 + 0) * 16384, g_Hdec + (si * 2 + 1) * 16384,
            g_Hdec + (so * 2 + 1) * 16384, outp, outp ? 1 : 0, t);
        }
        bar_dom(flags, acks, lb, tid, g);
      }
    }
    if (lb == 0 && tid == 0) sc_st_u32(&g_gen0_dec, g);
  }
}

// ---- deferred decoder LayerNorm over all 5 sentences (5120 rows) ------------
__global__ void __launch_bounds__(256) k_ln_post(Params P)
{
  const int blk = blockIdx.x, tid = threadIdx.x;
  const int lane = tid & 63, wave = tid >> 6;
#pragma unroll
  for (int rr = 0; rr < 2; rr++) {
    int row = blk * 8 + wave * 2 + rr;                    // 0..5119
    const u16* x = g_outsb5 + (size_t)row * 512 + lane * 8;
    float xs[8]; float sm = 0.f, sq = 0.f;
#pragma unroll
    for (int j = 0; j < 8; j++) { xs[j] = b2f(x[j]); sm += xs[j]; sq += xs[j] * xs[j]; }
#pragma unroll
    for (int off = 32; off; off >>= 1) { sm += __shfl_xor(sm, off, 64); sq += __shfl_xor(sq, off, 64); }
    float mean = sm * (1.f / 512.f);
    float var = fmaxf(sq * (1.f / 512.f) - mean * mean, 0.f);
    float rstd = rsqrtf(var + 1e-5f);
    u16* o = g_lnouts5 + (size_t)row * 512 + lane * 8;
#pragma unroll
    for (int j = 0; j < 8; j++) {
      int k = lane * 8 + j;
      o[j] = f2b((xs[j] - mean) * rstd * gc_dec_ln_g[k] + gc_dec_ln_b[k]);
    }
  }
}

// ---- deferred FC over all 5 sentences: logits -> out[b][s-1][t][v] ----------
__global__ void __launch_bounds__(256) k_fc_post(Params P)
{
  __shared__ char sbuf[65536];
  const int blk0 = blockIdx.x, tid = threadIdx.x;
  const int sidx = blk0 / 192, blk = blk0 % 192;
  const int lane = tid & 63, wave = tid >> 6;
  const int n = lane & 15, q = lane >> 4;
  const bool f32o = is_f32(P);
  const u16* lnin = g_lnouts5 + (size_t)sidx * 524288;
  u16* As = (u16*)sbuf;                  // [64 rows][512], XOR-swizzled 16B chunks
  int mc = blk / 12, ncc = blk % 12;
  int mrow0 = mc * 64;
  for (int idx = tid; idx < 64 * 64; idx += 256) {
    int row = idx >> 6, ch = idx & 63;
    int phys = ch ^ (row & 7);
    *(u32x4*)(As + (row * 64 + phys) * 8) = *(const u32x4*)(lnin + (size_t)(mrow0 + row) * 512 + ch * 8);
  }
  __syncthreads();
  f4 acc[4][8];
#pragma unroll
  for (int j = 0; j < 8; j++) {
    int c = ncc * 512 + wave * 128 + j * 16 + n;
    float bv = (c < 6000) ? gc_fc_b[c] : 0.f;
    f4 bi = { bv, bv, bv, bv };
#pragma unroll
    for (int mt = 0; mt < 4; mt++) acc[mt][j] = bi;
  }
  for (int kt = 0; kt < 16; kt++) {
    bf8 a[4];
#pragma unroll
    for (int mt = 0; mt < 4; mt++) {
      int row = mt * 16 + n;
      int ch = kt * 4 + q;
      int phys = ch ^ (row & 7);
      a[mt] = *(const bf8*)(As + (row * 64 + phys) * 8);
    }
#pragma unroll
    for (int j = 0; j < 8; j++) {
      int c = ncc * 512 + wave * 128 + j * 16 + n;
      int brow = (c < 6000) ? c : 5999;
      bf8 vb = *(const bf8*)(gb_fc_W + brow * 512 + kt * 32 + q * 8);
#pragma unroll
      for (int mt = 0; mt < 4; mt++)
        acc[mt][j] = __builtin_amdgcn_mfma_f32_16x16x32_bf16(a[mt], vb, acc[mt][j], 0, 0, 0);
    }
  }
#pragma unroll
  for (int j = 0; j < 8; j++) {
    int c = ncc * 512 + wave * 128 + j * 16 + n;
    if (c < 6000) {
#pragma unroll
      for (int mt = 0; mt < 4; mt++) {
#pragma unroll
        for (int r = 0; r < 4; r++) {
          int rix = mrow0 + mt * 16 + q * 4 + r;   // row = t*32 + b
          int tt = rix >> 5, b = rix & 31;
          size_t oidx = (size_t)((b * 5 + sidx) * 32 + tt) * 6000 + c;
          float v = acc[mt][j][r];
          if (f32o) ((float*)P.out)[oidx] = v;
          else      ((u16*)P.out)[oidx] = f2b(v);
        }
      }
    }
  }
}

extern "C" void kernel_launch(void* const* d_in, const int* in_sizes, int n_in,
                              void* d_out, int out_size, void* d_ws, size_t ws_size,
                              hipStream_t stream) {
  Params P;
  P.inputs   = (const int*)d_in[0];
  P.targets  = (const int*)d_in[1];
  P.enc_emb  = d_in[2];
  P.enc_Wih  = d_in[3];
  P.enc_Whh  = d_in[4];
  P.enc_bias = d_in[5];
  P.enc_ln_g = d_in[6];
  P.enc_ln_b = d_in[7];
  P.dec_emb  = d_in[8];
  P.att_W    = d_in[9];
  P.att_b    = d_in[10];
  P.att_v    = d_in[11];
  P.dec_Wih0 = d_in[12];
  P.dec_Wih1 = d_in[13];
  P.dec_Whh  = d_in[14];
  P.dec_bias = d_in[15];
  P.dec_ln_g = d_in[16];
  P.dec_ln_b = d_in[17];
  P.fc_W     = d_in[18];
  P.fc_b     = d_in[19];
  P.out = d_out;

  static bool attr_done = false;
  if (!attr_done) {
    hipFuncSetAttribute((const void*)k_persist,
                        hipFuncAttributeMaxDynamicSharedMemorySize, LDS_TOTAL);
    attr_done = true;
  }

  hipLaunchKernelGGL(k_conv, dim3(9364), dim3(256), 0, stream, P);
  hipLaunchKernelGGL(k_conv_small, dim3(68), dim3(256), 0, stream, P);
  hipLaunchKernelGGL(k_setup, dim3(256), dim3(256), 0, stream, P);
  hipLaunchKernelGGL(k_pre, dim3(2816), dim3(256), 0, stream);
  hipLaunchKernelGGL(k_persist, dim3(128), dim3(256), LDS_TOTAL, stream);
  hipLaunchKernelGGL(k_ln_post, dim3(640), dim3(256), 0, stream, P);
  hipLaunchKernelGGL(k_fc_post, dim3(960), dim3(256), 0, stream, P);
}

// Round 10
// 10977.575 us; speedup vs baseline: 1.5545x; 1.0484x over previous
//
#include <hip/hip_runtime.h>

typedef unsigned short u16;
typedef __attribute__((ext_vector_type(8))) short bf8;     // 8 x bf16 (4 VGPRs)
typedef __attribute__((ext_vector_type(4))) float f4;      // MFMA C/D frag
typedef __attribute__((ext_vector_type(4))) unsigned int u32x4;

struct Params {
  const int* inputs; const int* targets;
  const void *enc_emb, *enc_Wih, *enc_Whh, *enc_bias, *enc_ln_g, *enc_ln_b;
  const void *dec_emb, *att_W, *att_b, *att_v;
  const void *dec_Wih0, *dec_Wih1, *dec_Whh, *dec_bias, *dec_ln_g, *dec_ln_b;
  const void *fc_W, *fc_b;
  void* out;
};

// -------- canonical weight/vector buffers (filled by k_conv each launch) -----
__device__ __align__(16) u16 gb_enc_emb[3072000];
__device__ __align__(16) u16 gb_dec_emb[3072000];
__device__ __align__(16) u16 gb_enc_Wih[2097152];
__device__ __align__(16) u16 gb_enc_Whh[2097152];
__device__ __align__(16) u16 gb_dec_Wih0[2097152];
__device__ __align__(16) u16 gb_dec_Wih1[1048576];
__device__ __align__(16) u16 gb_dec_Whh[2097152];
__device__ __align__(16) u16 gb_att_W[524288];
__device__ __align__(16) u16 gb_fc_W[3072000];
__device__ float gc_enc_bias[4096], gc_dec_bias[4096];
__device__ float gc_enc_ln_g[512], gc_enc_ln_b[512], gc_dec_ln_g[512], gc_dec_ln_b[512];
__device__ float gc_att_b[512], gc_att_v[512], gc_fc_b[6000];

// ---------------- state scratch in device globals ----------------------------
__device__ __align__(16) u16 g_Hdec[4 * 32 * 512];       // [slot][layer][b][h]
__device__ __align__(16) u16 g_Henc[4 * 32 * 512];
__device__ __align__(16) u16 g_ctx[32 * 512];
__device__ __align__(16) u16 g_outsb5[5 * 1024 * 512];   // [s-1][t*32+b][h]
__device__ __align__(16) u16 g_lnouts5[5 * 1024 * 512];
__device__ __align__(16) u16 g_encraw5[5 * 1024 * 512];  // [s][b*32+t][h]
__device__ __align__(16) u16 g_encouts5[5 * 1024 * 512]; // [s][b*32+t][h]
__device__ __align__(16) u16 g_encpart5[5 * 1024 * 512];
__device__ int g_masks[6 * 32 * 32];
__device__ int g_dtoks[6 * 32 * 32];                     // [s][t][b]
__device__ int g_etoks[5 * 32 * 32];

// precomputed emb-input gate partials (bias folded in), layout [gstep][c 2048][b 32] f32
__device__ __align__(16) float g_dpre[192 * 2048 * 32];
__device__ __align__(16) float g_epre[160 * 2048 * 32];

// ---------------- barrier state (zero-init; monotonic across launches) -------
__device__ unsigned g_flags_enc[64 * 32];
__device__ unsigned g_flags_dec[64 * 32];
__device__ unsigned g_gen0_enc, g_gen0_dec, g_encdone, g_epoch;

// LDS layout for k_persist (dynamic shared)
#define GL_OFF   0          // gate exchange: 4*32*17*4 = 8704 B (also att scratch)
#define HL_OFF   8704       // (spare) 2048 B
#define CL_OFF   10752      // C state f32: 32*16*4 = 2048 B (block-private)
#define SEG1_OFF 12800      // weight seg 1: 4 waves * 16 rows * 512 u16 = 65536 B
#define SEG2_OFF 78336      // weight seg 2: 65536 B
#define LDS_TOTAL 143872

#define SPIN_CAP (1 << 27)   // deadlock -> wrong-answer safety valve (~seconds)

__device__ __forceinline__ float b2f(u16 u) { union { unsigned i; float f; } v; v.i = ((unsigned)u) << 16; return v.f; }
__device__ __forceinline__ u16 f2b(float f) {
  union { float f; unsigned i; } v; v.f = f;
  unsigned x = v.i;
  return (u16)((x + 0x7fffu + ((x >> 16) & 1u)) >> 16);    // RNE
}
__device__ __forceinline__ float sigf(float x) { return 1.f / (1.f + __expf(-x)); }
__device__ __forceinline__ float tanhf_(float x) { float e = __expf(2.f * x); return 1.f - 2.f / (e + 1.f); }

__device__ __forceinline__ bool is_f32(const Params& P) {
  return *(const unsigned*)P.enc_ln_g == 0x3F800000u;
}

// ---------------- LLC-coherent (sc0 sc1) access helpers ----------------------
#define VWAIT(N) do { asm volatile("s_waitcnt vmcnt(" #N ")" ::: "memory"); \
                      __builtin_amdgcn_sched_barrier(0); } while (0)

__device__ __forceinline__ void sc_ld(bf8& d, const u16* p) {
  asm volatile("global_load_dwordx4 %0, %1, off sc0 sc1" : "=v"(d) : "v"(p));
}
__device__ __forceinline__ void sc_st16(u16* p, u32x4 v) {
  asm volatile("global_store_dwordx4 %0, %1, off sc0 sc1" :: "v"(p), "v"(v) : "memory");
}
__device__ __forceinline__ void sc_st_u16(u16* p, u16 v) {
  unsigned vv = v;
  asm volatile("global_store_short %0, %1, off sc0 sc1" :: "v"(p), "v"(vv) : "memory");
}
__device__ __forceinline__ unsigned sc_ld_u32(const unsigned* p) {
  unsigned r;
  asm volatile("global_load_dword %0, %1, off sc0 sc1\n\ts_waitcnt vmcnt(0)"
               : "=v"(r) : "v"(p) : "memory");
  return r;
}
__device__ __forceinline__ void sc_st_u32(unsigned* p, unsigned v) {
  asm volatile("global_store_dword %0, %1, off sc0 sc1\n\ts_waitcnt vmcnt(0)"
               :: "v"(p), "v"(v) : "memory");
}

// ---------------- fence-free ALL-TO-ALL domain barrier (64 blocks) ------------
// Chain: per-wave vmcnt(0) drain -> own flag sc-store -> wave-0 lanes each poll
// ONE block's flag with signed->= compare (a fast block may already be a
// generation ahead). ~3 serial LLC RTs vs leader-ack's ~5. No cache
// invalidation anywhere. Spins capped: protocol bug => wrong-answer + counters,
// not an opaque hang.
__device__ __forceinline__ void bar_dom(unsigned* flags, int lb, int tid, unsigned& g) {
  g += 1;
  asm volatile("s_waitcnt vmcnt(0)" ::: "memory");
  __syncthreads();
  if (tid == 0) sc_st_u32(flags + lb * 32, g);
  if (tid < 64) {
    int it = 0;
    while ((int)(sc_ld_u32(flags + tid * 32) - g) < 0 && ++it < SPIN_CAP)
      __builtin_amdgcn_s_sleep(1);
  }
  __syncthreads();
}

struct Acc2 { f4 lo, hi; };

// C[0:32,0:16] += A[0:32,0:K] * Wp[0:16,0:K]^T (normal cached loads; immutable A/W)
__device__ __forceinline__ void mm_seg(Acc2& a, const u16* A, const u16* Wp, int ldW, int K, int lane) {
  const int n = lane & 15, q = lane >> 4;
  const u16* a0 = A + n * 512 + q * 8;
  const u16* a1 = a0 + 16 * 512;
  const u16* bp = Wp + n * ldW + q * 8;
  for (int k = 0; k < K; k += 32) {
    bf8 va0 = *(const bf8*)(a0 + k);
    bf8 va1 = *(const bf8*)(a1 + k);
    bf8 vb  = *(const bf8*)(bp + k);
    a.lo = __builtin_amdgcn_mfma_f32_16x16x32_bf16(va0, vb, a.lo, 0, 0, 0);
    a.hi = __builtin_amdgcn_mfma_f32_16x16x32_bf16(va1, vb, a.hi, 0, 0, 0);
  }
}

// A rows gathered from an embedding table by token id (K = 512, normal loads)
__device__ __forceinline__ void mm_tok(Acc2& a, const u16* emb, const int* toks,
                                       const u16* Wp, int ldW, int lane) {
  const int n = lane & 15, q = lane >> 4;
  const u16* a0 = emb + (size_t)toks[n] * 512 + q * 8;
  const u16* a1 = emb + (size_t)toks[n + 16] * 512 + q * 8;
  const u16* bp = Wp + n * ldW + q * 8;
  for (int k = 0; k < 512; k += 32) {
    bf8 va0 = *(const bf8*)(a0 + k);
    bf8 va1 = *(const bf8*)(a1 + k);
    bf8 vb  = *(const bf8*)(bp + k);
    a.lo = __builtin_amdgcn_mfma_f32_16x16x32_bf16(va0, vb, a.lo, 0, 0, 0);
    a.hi = __builtin_amdgcn_mfma_f32_16x16x32_bf16(va1, vb, a.hi, 0, 0, 0);
  }
}

// A[32][512] via coherent sc loads (all 32 issued upfront, descending counted
// vmcnt ladder -> one LLC latency per GEMM), W from LDS (XOR-swizzled)
__device__ __forceinline__ void mm_seg_llc(Acc2& a, const u16* A, const u16* Wl, int lane) {
  const int n = lane & 15, q = lane >> 4, x = n & 7;
  const u16* a0 = A + n * 512 + q * 8;
  const u16* a1 = a0 + 8192;                 // row n+16
  const u16* wr = Wl + n * 512;
  bf8 r0[4][4], r1[4][4];
#pragma unroll
  for (int c = 0; c < 4; c++)
#pragma unroll
    for (int j = 0; j < 4; j++) {
      sc_ld(r0[c][j], a0 + c * 128 + j * 32);
      sc_ld(r1[c][j], a1 + c * 128 + j * 32);
    }
#pragma unroll
  for (int c = 0; c < 4; c++) {
    if (c == 0) VWAIT(24); else if (c == 1) VWAIT(16); else if (c == 2) VWAIT(8); else VWAIT(0);
#pragma unroll
    for (int j = 0; j < 4; j++) {
      int ki = c * 4 + j;
      bf8 vb = *(const bf8*)(wr + (((q + 4 * ki) ^ x) << 3));
      a.lo = __builtin_amdgcn_mfma_f32_16x16x32_bf16(r0[c][j], vb, a.lo, 0, 0, 0);
      a.hi = __builtin_amdgcn_mfma_f32_16x16x32_bf16(r1[c][j], vb, a.hi, 0, 0, 0);
    }
  }
}

// stage a 64KB weight slice (4 waves x 16 rows x 512 cols) into LDS, swizzled
__device__ __forceinline__ void stage_seg(u16* lds_seg, const u16* W, int ldW, int c0, int u, int tid) {
  for (int idx = tid; idx < 4096; idx += 256) {
    int w = idx >> 10, n = (idx >> 6) & 15, ch = idx & 63;
    const u16* src = W + (size_t)(w * 512 + u * 16 + n) * ldW + c0 + ch * 8;
    u16* dst = lds_seg + ((w * 16 + n) * 64 + (ch ^ (n & 7))) * 8;
    *(u32x4*)dst = *(const u32x4*)src;
  }
}

// One LSTM layer step: weights in LDS, A via sc loads, C in LDS, H out via sc.
__device__ __forceinline__ void lstm_llc(char* smem, int u, int lane, int wave, int tid,
    const float* pre, const float* bias,
    const u16* A1, const u16* A2,
    u16* Hout, u16* Xtra, int xmode, int t)
{
  float* gl = (float*)(smem + GL_OFF);             // [4][32][17]
  float* Cl = (float*)(smem + CL_OFF);             // [32][16]
  const u16* seg1 = (const u16*)(smem + SEG1_OFF) + wave * 8192;
  const u16* seg2 = (const u16*)(smem + SEG2_OFF) + wave * 8192;
  const int n = lane & 15, q = lane >> 4;
  const int colbase = wave * 512 + u * 16;
  Acc2 acc;
  if (pre) {
    const float* pb = pre + (size_t)(colbase + n) * 32;
    acc.lo = *(const f4*)(pb + q * 4);
    acc.hi = *(const f4*)(pb + q * 4 + 16);
  } else {
    float bv = bias[colbase + n];
    f4 bi = { bv, bv, bv, bv };
    acc.lo = bi; acc.hi = bi;
  }
  if (A1) mm_seg_llc(acc, A1, seg1, lane);
  if (A2) mm_seg_llc(acc, A2, seg2, lane);
#pragma unroll
  for (int r = 0; r < 4; r++) {
    gl[(wave * 32 + q * 4 + r) * 17 + n]      = acc.lo[r];
    gl[(wave * 32 + 16 + q * 4 + r) * 17 + n] = acc.hi[r];
  }
  __syncthreads();
  for (int p = tid; p < 512; p += 256) {
    int b = p >> 4, nn = p & 15, hc = u * 16 + nn;
    float iv = gl[(0 * 32 + b) * 17 + nn];
    float fv = gl[(1 * 32 + b) * 17 + nn];
    float gv = gl[(2 * 32 + b) * 17 + nn];
    float ov = gl[(3 * 32 + b) * 17 + nn];
    float c2 = sigf(fv) * Cl[b * 16 + nn] + sigf(iv) * tanhf_(gv);
    float h2 = sigf(ov) * tanhf_(c2);
    Cl[b * 16 + nn] = c2;
    u16 hb = f2b(h2);
    sc_st_u16(Hout + b * 512 + hc, hb);
    if (xmode == 1)      Xtra[(t * 32 + b) * 512 + hc] = hb;          // outsb5 (normal)
    else if (xmode == 2) sc_st_u16(Xtra + (b * 32 + t) * 512 + hc, hb); // encraw (sc)
  }
}

// attention for batch row b (one block), result -> g_ctx[b][:] (sc).
// qp = h1[b,:] @ attW[:, :512]^T computed HERE from L2-resident attW (no pqp
// global round-trip; h1 read via sc, 1 KB).
__device__ __forceinline__ void att_llc(char* smem, int b, int s, int si, int lane, int wave, int tid)
{
  float* qp  = (float*)(smem + GL_OFF);
  float* sc  = qp + 512;
  float* av  = sc + 32;
  float* hlf = av + 32;                                  // [512] f32
  const u16* ep_prev = g_encpart5 + (size_t)(s - 1) * 524288;
  const u16* eo_prev = g_encouts5 + (size_t)(s - 1) * 524288;
  const u16* h1 = g_Hdec + (si * 2 + 1) * 16384 + b * 512;

  if (wave == 0) {                                       // load h1 -> LDS f32
    bf8 v; sc_ld(v, h1 + lane * 8);
    VWAIT(0);
#pragma unroll
    for (int j = 0; j < 8; j++) hlf[lane * 8 + j] = b2f((u16)v[j]);
  }
  __syncthreads();
  for (int h = tid; h < 512; h += 256) {
    const u16* wrow = gb_att_W + (size_t)h * 1024;       // first 512 cols
    float acc = 0.f;
#pragma unroll 8
    for (int kk = 0; kk < 64; kk++) {
      bf8 w = *(const bf8*)(wrow + kk * 8);
#pragma unroll
      for (int j = 0; j < 8; j++) acc += hlf[kk * 8 + j] * b2f((u16)w[j]);
    }
    qp[h] = acc;
  }
  __syncthreads();
  for (int tt = wave; tt < 32; tt += 4) {
    float part = 0.f;
    for (int h = lane; h < 512; h += 64)
      part += tanhf_(qp[h] + b2f(ep_prev[(b * 32 + tt) * 512 + h])) * gc_att_v[h];
#pragma unroll
    for (int off = 32; off; off >>= 1) part += __shfl_xor(part, off, 64);
    if (lane == 0) sc[tt] = g_masks[(s * 32 + b) * 32 + tt] ? -1e9f : fminf(fmaxf(part, -1e30f), 1e30f);
  }
  __syncthreads();
  if (wave == 0) {
    float v = (lane < 32) ? sc[lane] : -3e38f;
    float m = v;
#pragma unroll
    for (int off = 32; off; off >>= 1) m = fmaxf(m, __shfl_xor(m, off, 64));
    float e = (lane < 32) ? __expf(v - m) : 0.f;
    float ssum = e;
#pragma unroll
    for (int off = 32; off; off >>= 1) ssum += __shfl_xor(ssum, off, 64);
    if (lane < 32) av[lane] = e / ssum;
  }
  __syncthreads();
  for (int h = tid; h < 512; h += 256) {
    float ssum = 0.f;
#pragma unroll 4
    for (int tt = 0; tt < 32; tt++) ssum += av[tt] * b2f(eo_prev[(b * 32 + tt) * 512 + h]);
    sc_st_u16(g_ctx + b * 512 + h, f2b(ssum));
  }
}

// ---------------------------- kernels ----------------------------------------

__global__ void __launch_bounds__(256) k_conv(Params P)
{
  const bool f32 = is_f32(P);
  int c = blockIdx.x * 256 + threadIdx.x;    // chunk of 8 elements
  const void* src; u16* dst;
  if (c < 384000)                 { src = P.enc_emb;  dst = gb_enc_emb;  }
  else if ((c -= 384000) < 384000){ src = P.dec_emb;  dst = gb_dec_emb;  }
  else if ((c -= 384000) < 262144){ src = P.enc_Wih;  dst = gb_enc_Wih;  }
  else if ((c -= 262144) < 262144){ src = P.enc_Whh;  dst = gb_enc_Whh;  }
  else if ((c -= 262144) < 262144){ src = P.dec_Wih0; dst = gb_dec_Wih0; }
  else if ((c -= 262144) < 131072){ src = P.dec_Wih1; dst = gb_dec_Wih1; }
  else if ((c -= 131072) < 262144){ src = P.dec_Whh;  dst = gb_dec_Whh;  }
  else if ((c -= 262144) < 65536) { src = P.att_W;    dst = gb_att_W;    }
  else                            { c -= 65536; src = P.fc_W; dst = gb_fc_W; }
  if (f32) {
    const float* s = (const float*)src + (size_t)c * 8;
    union { u32x4 v; u16 o[8]; } u;
#pragma unroll
    for (int j = 0; j < 8; j++) u.o[j] = f2b(s[j]);
    *(u32x4*)(dst + (size_t)c * 8) = u.v;
  } else {
    ((u32x4*)dst)[c] = ((const u32x4*)src)[c];
  }
}

__global__ void __launch_bounds__(256) k_conv_small(Params P)
{
  const bool f32 = is_f32(P);
  int i = blockIdx.x * 256 + threadIdx.x;
  const void* src; float* dst;
  if (i < 4096)                 { src = P.enc_bias; dst = gc_enc_bias; }
  else if ((i -= 4096) < 4096)  { src = P.dec_bias; dst = gc_dec_bias; }
  else if ((i -= 4096) < 512)   { src = P.enc_ln_g; dst = gc_enc_ln_g; }
  else if ((i -= 512) < 512)    { src = P.enc_ln_b; dst = gc_enc_ln_b; }
  else if ((i -= 512) < 512)    { src = P.dec_ln_g; dst = gc_dec_ln_g; }
  else if ((i -= 512) < 512)    { src = P.dec_ln_b; dst = gc_dec_ln_b; }
  else if ((i -= 512) < 512)    { src = P.att_b;    dst = gc_att_b;    }
  else if ((i -= 512) < 512)    { src = P.att_v;    dst = gc_att_v;    }
  else if ((i -= 512) < 6000)   { src = P.fc_b;     dst = gc_fc_b;     }
  else return;
  dst[i] = f32 ? ((const float*)src)[i] : b2f(((const u16*)src)[i]);
}

__global__ void __launch_bounds__(256) k_setup(Params P)
{
  const int gtid = blockIdx.x * 256 + threadIdx.x;
  if (gtid == 0) g_epoch = g_epoch + 1;
  if (gtid < 6144) {                      // dtoks[s][t][b]
    int s = gtid >> 10, rem = gtid & 1023, t = rem >> 5, b = rem & 31;
    int tok = (t == 0) ? 1
            : ((s == 0) ? P.inputs[b * 192 + (t - 1)] : P.targets[b * 160 + (s - 1) * 32 + (t - 1)]);
    g_dtoks[gtid] = tok;
  } else if (gtid < 6144 + 5120) {        // etoks[s][t][b]
    int gi = gtid - 6144;
    int s = gi >> 10, rem = gi & 1023, t = rem >> 5, b = rem & 31;
    g_etoks[gi] = (s == 0) ? P.inputs[b * 192 + t] : P.targets[b * 160 + (s - 1) * 32 + t];
  }
  if (blockIdx.x >= 64 && blockIdx.x < 224 && threadIdx.x == 0) {  // masks[s][b][t]
    int w = blockIdx.x - 64;
    int s = 1 + (w >> 5), b = w & 31;
    int seen = 0;
    g_masks[(s * 32 + b) * 32 + 0] = 0;
    for (int t2 = 1; t2 < 32; t2++) {
      int tk = (s == 1) ? P.inputs[b * 192 + (t2 - 1)] : P.targets[b * 160 + (s - 2) * 32 + (t2 - 1)];
      seen |= (tk == 2 || tk == 3) ? 1 : 0;
      g_masks[(s * 32 + b) * 32 + t2] = seen;
    }
  }
  u32x4 z = { 0u, 0u, 0u, 0u };
  if (gtid < 8192)  ((u32x4*)g_Hdec)[gtid] = z;
  if (gtid >= 8192 && gtid < 16384) ((u32x4*)g_Henc)[gtid - 8192] = z;
  if (gtid >= 16384 && gtid < 18432) ((u32x4*)g_ctx)[gtid - 16384] = z;
}

// precompute emb-input gate partials for all timesteps
__global__ void __launch_bounds__(256) k_pre()
{
  const int blk = blockIdx.x, tid = threadIdx.x;
  const int lane = tid & 63, wave = tid >> 6;
  const int n = lane & 15, q = lane >> 4;
  const bool dec = blk < 1536;
  const int idx = dec ? blk : blk - 1536;
  const int u = idx & 31, gq = idx >> 5;
  const u16* emb = dec ? gb_dec_emb : gb_enc_emb;
  const u16* W   = dec ? gb_dec_Wih0 : gb_enc_Wih;
  const int ldW  = dec ? 1024 : 512;
  const float* bias = dec ? gc_dec_bias : gc_enc_bias;
  float* pre = dec ? g_dpre : g_epre;
  const int* toks = dec ? g_dtoks : g_etoks;
  const int colbase = wave * 512 + u * 16;
  for (int gi = 0; gi < 4; gi++) {
    int gstep = gq * 4 + gi;
    float bv = bias[colbase + n];
    f4 bi = { bv, bv, bv, bv };
    Acc2 acc; acc.lo = bi; acc.hi = bi;
    mm_tok(acc, emb, toks + gstep * 32, W + (size_t)colbase * ldW, ldW, lane);
    float* dst = pre + ((size_t)gstep * 2048 + colbase + n) * 32;
    *(f4*)(dst + q * 4) = acc.lo;
    *(f4*)(dst + q * 4 + 16) = acc.hi;
  }
}

// ---------------- the persistent recurrence kernel ---------------------------
// 128 blocks, 1/CU. Two independent barrier domains:
//   enc = blocks 0-63  (role 0: enc L0, role 1: enc L1), 2 phases/step
//   dec = blocks 64-127 (role 0: att+dec L0, role 1: dec L1), 3 phases/step
// enc runs ahead; dec waits on a per-sentence enc_done flag. No cache fences:
// all racy state moves via sc0 sc1 (LLC) accesses; read-only data stays L2-hot.
__global__ void __launch_bounds__(256) k_persist()
{
  extern __shared__ char smem[];
  const int blk = blockIdx.x, tid = threadIdx.x;
  const int lane = tid & 63, wave = tid >> 6;
  const bool encdom = blk < 64;
  const int lb = encdom ? blk : blk - 64;
  const int role = lb >> 5, u = lb & 31;
  const unsigned epoch = g_epoch;

  { float* Cl = (float*)(smem + CL_OFF); for (int i = tid; i < 512; i += 256) Cl[i] = 0.f; }

  u16* s1 = (u16*)(smem + SEG1_OFF);
  u16* s2 = (u16*)(smem + SEG2_OFF);
  if (encdom) {
    if (role == 0) {
      stage_seg(s1, gb_enc_Whh, 512, 0, u, tid);
    } else {
      stage_seg(s1, gb_enc_Wih + 1048576, 512, 0, u, tid);
      stage_seg(s2, gb_enc_Whh + 1048576, 512, 0, u, tid);
    }
  } else {
    if (role == 0) {
      stage_seg(s1, gb_dec_Wih0, 1024, 512, u, tid);
      stage_seg(s2, gb_dec_Whh, 512, 0, u, tid);
    } else {
      stage_seg(s1, gb_dec_Wih1, 512, 0, u, tid);
      stage_seg(s2, gb_dec_Whh + 1048576, 512, 0, u, tid);
    }
  }
  __syncthreads();

  unsigned* flags = encdom ? g_flags_enc : g_flags_dec;
  unsigned g = sc_ld_u32(encdom ? &g_gen0_enc : &g_gen0_dec);

  if (encdom) {
    for (int s = 0; s < 5; s++) {
      for (int t = 0; t < 32; t++) {
        const int gstep = s * 32 + t, si = gstep & 1, so = si ^ 1;
        if (role == 0)
          lstm_llc(smem, u, lane, wave, tid,
            g_epre + (size_t)gstep * 65536, nullptr,
            g_Henc + (si * 2 + 0) * 16384, nullptr,
            g_Henc + (so * 2 + 0) * 16384, nullptr, 0, t);
        bar_dom(flags, lb, tid, g);
        if (role == 1)
          lstm_llc(smem, u, lane, wave, tid,
            nullptr, gc_enc_bias + 2048,
            g_Henc + (so * 2 + 0) * 16384, g_Henc + (si * 2 + 1) * 16384,
            g_Henc + (so * 2 + 1) * 16384, g_encraw5 + (size_t)s * 524288, 2, t);
        bar_dom(flags, lb, tid, g);
      }
      // ---- enc LayerNorm: 1024 rows over 64 blocks (16 rows each) ----
      {
        const u16* in = g_encraw5 + (size_t)s * 524288;    // sc-written, first-touch
        u16* out = g_encouts5 + (size_t)s * 524288;
#pragma unroll
        for (int rr = 0; rr < 4; rr++) {
          int row = lb * 16 + wave * 4 + rr;
          const u16* x = in + row * 512 + lane * 8;
          float xs[8]; float sm = 0.f, sq = 0.f;
#pragma unroll
          for (int j = 0; j < 8; j++) { xs[j] = b2f(x[j]); sm += xs[j]; sq += xs[j] * xs[j]; }
#pragma unroll
          for (int off = 32; off; off >>= 1) { sm += __shfl_xor(sm, off, 64); sq += __shfl_xor(sq, off, 64); }
          float mean = sm * (1.f / 512.f);
          float var = fmaxf(sq * (1.f / 512.f) - mean * mean, 0.f);
          float rstd = rsqrtf(var + 1e-5f);
          union { u32x4 v; u16 o[8]; } pk;
#pragma unroll
          for (int j = 0; j < 8; j++) {
            int k = lane * 8 + j;
            pk.o[j] = f2b((xs[j] - mean) * rstd * gc_enc_ln_g[k] + gc_enc_ln_b[k]);
          }
          sc_st16(out + row * 512 + lane * 8, pk.v);
        }
      }
      bar_dom(flags, lb, tid, g);
      // ---- encpart[b][t][h] = enc_outs . att_W[:,512:] + att_b ----
      {
        const u16* eo = g_encouts5 + (size_t)s * 524288;   // sc-written, first-touch
        u16* ep = g_encpart5 + (size_t)s * 524288;
        const int n = lane & 15, q = lane >> 4;
        int rc = lb >> 3, cc = lb & 7;
        int nbase = cc * 64 + wave * 16;
        float bv = gc_att_b[nbase + n];
#pragma unroll
        for (int mt = 0; mt < 4; mt++) {
          int rowbase = rc * 128 + mt * 32;
          f4 bi = { bv, bv, bv, bv };
          Acc2 acc; acc.lo = bi; acc.hi = bi;
          mm_seg(acc, eo + rowbase * 512, gb_att_W + nbase * 1024 + 512, 1024, 512, lane);
#pragma unroll
          for (int r = 0; r < 4; r++) {
            int row = rowbase + q * 4 + r;
            sc_st_u16(ep + row * 512 + nbase + n, f2b(acc.lo[r]));
            sc_st_u16(ep + (row + 16) * 512 + nbase + n, f2b(acc.hi[r]));
          }
        }
      }
      bar_dom(flags, lb, tid, g);
      if (lb == 0 && tid == 0) sc_st_u32(&g_encdone, epoch * 8u + (unsigned)s + 1u);
    }
    if (lb == 0 && tid == 0) sc_st_u32(&g_gen0_enc, g);
  } else {
    for (int s = 0; s < 6; s++) {
      if (s >= 1) {
        if (tid == 0) {
          unsigned tgt = epoch * 8u + (unsigned)s;
          int it = 0;
          while ((int)(sc_ld_u32(&g_encdone) - tgt) < 0 && ++it < SPIN_CAP)
            __builtin_amdgcn_s_sleep(8);
        }
        __syncthreads();
      }
      for (int t = 0; t < 32; t++) {
        const int gstep = s * 32 + t, si = gstep & 1, so = si ^ 1;
        // P1: attention (role 0, s>0) — h1 prev lives in slot (si*2+1)
        if (role == 0 && s > 0) att_llc(smem, u, s, si, lane, wave, tid);
        bar_dom(flags, lb, tid, g);
        // P2: dec L0 (role 0)
        if (role == 0)
          lstm_llc(smem, u, lane, wave, tid,
            g_dpre + (size_t)gstep * 65536, nullptr,
            (s > 0) ? g_ctx : nullptr, g_Hdec + (si * 2 + 0) * 16384,
            g_Hdec + (so * 2 + 0) * 16384, nullptr, 0, t);
        bar_dom(flags, lb, tid, g);
        // P3: dec L1 (role 1)
        if (role == 1) {
          u16* outp = (s >= 1) ? (g_outsb5 + (size_t)(s - 1) * 524288) : nullptr;
          lstm_llc(smem, u, lane, wave, tid,
            nullptr, gc_dec_bias + 2048,
            g_Hdec + (so * 2 + 0) * 16384, g_Hdec + (si * 2 + 1) * 16384,
            g_Hdec + (so * 2 + 1) * 16384, outp, outp ? 1 : 0, t);
        }
        bar_dom(flags, lb, tid, g);
      }
    }
    if (lb == 0 && tid == 0) sc_st_u32(&g_gen0_dec, g);
  }
}

// ---- deferred decoder LayerNorm over all 5 sentences (5120 rows) ------------
__global__ void __launch_bounds__(256) k_ln_post(Params P)
{
  const int blk = blockIdx.x, tid = threadIdx.x;
  const int lane = tid & 63, wave = tid >> 6;
#pragma unroll
  for (int rr = 0; rr < 2; rr++) {
    int row = blk * 8 + wave * 2 + rr;                    // 0..5119
    const u16* x = g_outsb5 + (size_t)row * 512 + lane * 8;
    float xs[8]; float sm = 0.f, sq = 0.f;
#pragma unroll
    for (int j = 0; j < 8; j++) { xs[j] = b2f(x[j]); sm += xs[j]; sq += xs[j] * xs[j]; }
#pragma unroll
    for (int off = 32; off; off >>= 1) { sm += __shfl_xor(sm, off, 64); sq += __shfl_xor(sq, off, 64); }
    float mean = sm * (1.f / 512.f);
    float var = fmaxf(sq * (1.f / 512.f) - mean * mean, 0.f);
    float rstd = rsqrtf(var + 1e-5f);
    u16* o = g_lnouts5 + (size_t)row * 512 + lane * 8;
#pragma unroll
    for (int j = 0; j < 8; j++) {
      int k = lane * 8 + j;
      o[j] = f2b((xs[j] - mean) * rstd * gc_dec_ln_g[k] + gc_dec_ln_b[k]);
    }
  }
}

// ---- deferred FC over all 5 sentences: logits -> out[b][s-1][t][v] ----------
__global__ void __launch_bounds__(256) k_fc_post(Params P)
{
  __shared__ char sbuf[65536];
  const int blk0 = blockIdx.x, tid = threadIdx.x;
  const int sidx = blk0 / 192, blk = blk0 % 192;
  const int lane = tid & 63, wave = tid >> 6;
  const int n = lane & 15, q = lane >> 4;
  const bool f32o = is_f32(P);
  const u16* lnin = g_lnouts5 + (size_t)sidx * 524288;
  u16* As = (u16*)sbuf;                  // [64 rows][512], XOR-swizzled 16B chunks
  int mc = blk / 12, ncc = blk % 12;
  int mrow0 = mc * 64;
  for (int idx = tid; idx < 64 * 64; idx += 256) {
    int row = idx >> 6, ch = idx & 63;
    int phys = ch ^ (row & 7);
    *(u32x4*)(As + (row * 64 + phys) * 8) = *(const u32x4*)(lnin + (size_t)(mrow0 + row) * 512 + ch * 8);
  }
  __syncthreads();
  f4 acc[4][8];
#pragma unroll
  for (int j = 0; j < 8; j++) {
    int c = ncc * 512 + wave * 128 + j * 16 + n;
    float bv = (c < 6000) ? gc_fc_b[c] : 0.f;
    f4 bi = { bv, bv, bv, bv };
#pragma unroll
    for (int mt = 0; mt < 4; mt++) acc[mt][j] = bi;
  }
  for (int kt = 0; kt < 16; kt++) {
    bf8 a[4];
#pragma unroll
    for (int mt = 0; mt < 4; mt++) {
      int row = mt * 16 + n;
      int ch = kt * 4 + q;
      int phys = ch ^ (row & 7);
      a[mt] = *(const bf8*)(As + (row * 64 + phys) * 8);
    }
#pragma unroll
    for (int j = 0; j < 8; j++) {
      int c = ncc * 512 + wave * 128 + j * 16 + n;
      int brow = (c < 6000) ? c : 5999;
      bf8 vb = *(const bf8*)(gb_fc_W + brow * 512 + kt * 32 + q * 8);
#pragma unroll
      for (int mt = 0; mt < 4; mt++)
        acc[mt][j] = __builtin_amdgcn_mfma_f32_16x16x32_bf16(a[mt], vb, acc[mt][j], 0, 0, 0);
    }
  }
#pragma unroll
  for (int j = 0; j < 8; j++) {
    int c = ncc * 512 + wave * 128 + j * 16 + n;
    if (c < 6000) {
#pragma unroll
      for (int mt = 0; mt < 4; mt++) {
#pragma unroll
        for (int r = 0; r < 4; r++) {
          int rix = mrow0 + mt * 16 + q * 4 + r;   // row = t*32 + b
          int tt = rix >> 5, b = rix & 31;
          size_t oidx = (size_t)((b * 5 + sidx) * 32 + tt) * 6000 + c;
          float v = acc[mt][j][r];
          if (f32o) ((float*)P.out)[oidx] = v;
          else      ((u16*)P.out)[oidx] = f2b(v);
        }
      }
    }
  }
}

extern "C" void kernel_launch(void* const* d_in, const int* in_sizes, int n_in,
                              void* d_out, int out_size, void* d_ws, size_t ws_size,
                              hipStream_t stream) {
  Params P;
  P.inputs   = (const int*)d_in[0];
  P.targets  = (const int*)d_in[1];
  P.enc_emb  = d_in[2];
  P.enc_Wih  = d_in[3];
  P.enc_Whh  = d_in[4];
  P.enc_bias = d_in[5];
  P.enc_ln_g = d_in[6];
  P.enc_ln_b = d_in[7];
  P.dec_emb  = d_in[8];
  P.att_W    = d_in[9];
  P.att_b    = d_in[10];
  P.att_v    = d_in[11];
  P.dec_Wih0 = d_in[12];
  P.dec_Wih1 = d_in[13];
  P.dec_Whh  = d_in[14];
  P.dec_bias = d_in[15];
  P.dec_ln_g = d_in[16];
  P.dec_ln_b = d_in[17];
  P.fc_W     = d_in[18];
  P.fc_b     = d_in[19];
  P.out = d_out;

  static bool attr_done = false;
  if (!attr_done) {
    hipFuncSetAttribute((const void*)k_persist,
                        hipFuncAttributeMaxDynamicSharedMemorySize, LDS_TOTAL);
    attr_done = true;
  }

  hipLaunchKernelGGL(k_conv, dim3(9364), dim3(256), 0, stream, P);
  hipLaunchKernelGGL(k_conv_small, dim3(68), dim3(256), 0, stream, P);
  hipLaunchKernelGGL(k_setup, dim3(256), dim3(256), 0, stream, P);
  hipLaunchKernelGGL(k_pre, dim3(2816), dim3(256), 0, stream);
  hipLaunchKernelGGL(k_persist, dim3(128), dim3(256), LDS_TOTAL, stream);
  hipLaunchKernelGGL(k_ln_post, dim3(640), dim3(256), 0, stream, P);
  hipLaunchKernelGGL(k_fc_post, dim3(960), dim3(256), 0, stream, P);
}